// Round 1
// baseline (3123.695 us; speedup 1.0000x reference)
//
#include <hip/hip_runtime.h>
#include <math.h>

#define D_MODEL 2048
#define D_INNER 4096
#define D_STATE 16
#define D_CONV  4
#define DT_RANK 128
#define NB      2
#define TT      1024
#define M_TOT   (NB * TT)          // 2048 rows for all GEMMs

// ---------------------------------------------------------------------------
// Generic C = A(M,K; lda) @ W(N,K; row-major)^T, fp32, tile 64x64x16,
// 256 threads, 4x4 accum per thread.  EPI: 0 = none, 1 = +bias then softplus.
// ---------------------------------------------------------------------------
template <int EPI>
__global__ __launch_bounds__(256) void gemm_nt(
    const float* __restrict__ A, int lda,
    const float* __restrict__ W,            // (N, K) row-major
    float* __restrict__ C, int ldc,
    int M, int N, int K,
    const float* __restrict__ bias)
{
    __shared__ __align__(16) float As[16][68];
    __shared__ __align__(16) float Ws[16][68];

    const int tid = threadIdx.x;
    const int tx = tid & 15, ty = tid >> 4;
    const int m0 = blockIdx.y * 64, n0 = blockIdx.x * 64;
    const int lr = tid >> 4;   // 0..15: row within 16-row load group
    const int lk = tid & 15;   // 0..15: k within tile

    float acc[4][4] = {};

    for (int k0 = 0; k0 < K; k0 += 16) {
#pragma unroll
        for (int i = 0; i < 4; i++) {
            int m = m0 + lr + i * 16;
            As[lk][lr + i * 16] = (m < M) ? A[(long)m * lda + k0 + lk] : 0.f;
        }
#pragma unroll
        for (int i = 0; i < 4; i++) {
            int n = n0 + lr + i * 16;
            Ws[lk][lr + i * 16] = (n < N) ? W[(long)n * K + k0 + lk] : 0.f;
        }
        __syncthreads();
#pragma unroll
        for (int kk = 0; kk < 16; kk++) {
            float a[4], b[4];
            *(float4*)a = *(const float4*)&As[kk][ty * 4];
            *(float4*)b = *(const float4*)&Ws[kk][tx * 4];
#pragma unroll
            for (int i = 0; i < 4; i++)
#pragma unroll
                for (int j = 0; j < 4; j++)
                    acc[i][j] += a[i] * b[j];
        }
        __syncthreads();
    }

#pragma unroll
    for (int i = 0; i < 4; i++) {
        int m = m0 + ty * 4 + i;
        if (m >= M) continue;
#pragma unroll
        for (int j = 0; j < 4; j++) {
            int n = n0 + tx * 4 + j;
            if (n >= N) continue;
            float v = acc[i][j];
            if (EPI == 1) {
                v += bias[n];
                v = (v > 20.f) ? v : log1pf(__expf(v));  // softplus
            }
            C[(long)m * ldc + n] = v;
        }
    }
}

// ---------------------------------------------------------------------------
// Causal depthwise conv (width 4) + bias + silu, with history cache.
// xi lives in xz[:, 0:4096] (row stride 8192).  Writes xs (2048,4096) and
// new_conv_cache (B, D_INNER, 3).
// grid: (T/128, D_INNER/256, B), block 256.
// ---------------------------------------------------------------------------
__global__ __launch_bounds__(256) void conv_silu(
    const float* __restrict__ xz,
    const float* __restrict__ conv_cache,   // (B, D_INNER, 3)
    const float* __restrict__ conv_w,       // (D_INNER, 4)
    const float* __restrict__ conv_b,
    float* __restrict__ xs,                 // (2048, 4096)
    float* __restrict__ cc_out)             // (B, D_INNER, 3)
{
    const int b  = blockIdx.z;
    const int d  = blockIdx.y * 256 + threadIdx.x;
    const int t0 = blockIdx.x * 128;

    const float4 w  = *(const float4*)&conv_w[d * 4];
    const float bias = conv_b[d];

    float xm3, xm2, xm1;
    if (t0 == 0) {
        xm3 = conv_cache[(b * D_INNER + d) * 3 + 0];
        xm2 = conv_cache[(b * D_INNER + d) * 3 + 1];
        xm1 = conv_cache[(b * D_INNER + d) * 3 + 2];
    } else {
        xm3 = xz[(long)(b * TT + t0 - 3) * 8192 + d];
        xm2 = xz[(long)(b * TT + t0 - 2) * 8192 + d];
        xm1 = xz[(long)(b * TT + t0 - 1) * 8192 + d];
    }

    for (int t = t0; t < t0 + 128; t++) {
        float xc = xz[(long)(b * TT + t) * 8192 + d];
        float v  = xm3 * w.x + xm2 * w.y + xm1 * w.z + xc * w.w + bias;
        float s  = v / (1.f + __expf(-v));          // silu
        xs[(long)(b * TT + t) * 4096 + d] = s;
        xm3 = xm2; xm2 = xm1; xm1 = xc;
    }

    if (t0 + 128 == TT) {   // last chunk holds xi[T-3..T-1] in the window
        cc_out[(b * D_INNER + d) * 3 + 0] = xm3;
        cc_out[(b * D_INNER + d) * 3 + 1] = xm2;
        cc_out[(b * D_INNER + d) * 3 + 2] = xm1;
    }
}

// ---------------------------------------------------------------------------
// Selective scan: one thread per (b, d), 16 states in registers.
// delta lives in xz[:, 0:4096] (written by dt_proj GEMM, ldc=8192),
// z in xz[:, 4096:8192].  B/C in dbc[:, 128:160].  Rewrites xs in-place with
// (y + D*xs) * silu(z).  Writes h_last.
// ---------------------------------------------------------------------------
__global__ __launch_bounds__(256) void scan_kernel(
    const float* __restrict__ xz,
    const float* __restrict__ dbc,          // (2048, 160)
    float* __restrict__ xs,                 // in: xs, out: gated y
    const float* __restrict__ h_in,         // (B, D_INNER, 16)
    const float* __restrict__ A_log,        // (D_INNER, 16)
    const float* __restrict__ D_param,      // (D_INNER,)
    float* __restrict__ h_out)              // (B, D_INNER, 16)
{
    const int idx = blockIdx.x * 256 + threadIdx.x;   // 0..8191
    const int b = idx >> 12;
    const int d = idx & 4095;

    float Ad[16], h[16];
#pragma unroll
    for (int n = 0; n < 16; n++) Ad[n] = -__expf(A_log[d * 16 + n]);
#pragma unroll
    for (int n = 0; n < 16; n++) h[n] = h_in[(b * D_INNER + d) * 16 + n];
    const float Dp = D_param[d];

    for (int t = 0; t < TT; t++) {
        const long base = (long)(b * TT + t);
        const float delta = xz[base * 8192 + d];
        const float zv    = xz[base * 8192 + 4096 + d];
        const float xv    = xs[base * 4096 + d];

        float Bv[16], Cv[16];
#pragma unroll
        for (int q = 0; q < 4; q++) {
            *(float4*)&Bv[q * 4] = *(const float4*)&dbc[base * 160 + 128 + q * 4];
            *(float4*)&Cv[q * 4] = *(const float4*)&dbc[base * 160 + 144 + q * 4];
        }

        float y = 0.f;
        const float dx = delta * xv;
#pragma unroll
        for (int n = 0; n < 16; n++) {
            float dA = __expf(delta * Ad[n]);
            h[n] = dA * h[n] + dx * Bv[n];
            y += h[n] * Cv[n];
        }
        y += Dp * xv;
        float g = zv / (1.f + __expf(-zv));           // silu(z)
        xs[base * 4096 + d] = y * g;
    }

#pragma unroll
    for (int n = 0; n < 16; n++) h_out[(b * D_INNER + d) * 16 + n] = h[n];
}

// ---------------------------------------------------------------------------
extern "C" void kernel_launch(void* const* d_in, const int* in_sizes, int n_in,
                              void* d_out, int out_size, void* d_ws, size_t ws_size,
                              hipStream_t stream)
{
    const float* x          = (const float*)d_in[0];   // (B,T,2048)
    const float* h_in       = (const float*)d_in[1];   // (B,4096,16)
    const float* conv_cache = (const float*)d_in[2];   // (B,4096,3)
    const float* in_proj_w  = (const float*)d_in[3];   // (8192,2048)
    const float* conv_w     = (const float*)d_in[4];   // (4096,4)
    const float* conv_b     = (const float*)d_in[5];   // (4096,)
    const float* x_proj_w   = (const float*)d_in[6];   // (160,4096)
    const float* dt_proj_w  = (const float*)d_in[7];   // (4096,128)
    const float* dt_proj_b  = (const float*)d_in[8];   // (4096,)
    const float* A_log      = (const float*)d_in[9];   // (4096,16)
    const float* D_param    = (const float*)d_in[10];  // (4096,)
    const float* out_proj_w = (const float*)d_in[11];  // (2048,4096)

    float* out    = (float*)d_out;                       // (B,T,2048)
    float* h_out  = (float*)d_out + (long)NB * TT * D_MODEL;           // 4194304
    float* cc_out = h_out + (long)NB * D_INNER * D_STATE;              // +131072

    char* ws = (char*)d_ws;
    float* xz  = (float*)(ws);                                         // (2048,8192) 64MB
    float* xs  = (float*)(ws + (size_t)M_TOT * 8192 * 4);              // (2048,4096) 32MB
    float* dbc = (float*)(ws + (size_t)M_TOT * 8192 * 4
                             + (size_t)M_TOT * 4096 * 4);              // (2048,160)

    dim3 blk(256);

    // 1) xz = x @ in_proj_w^T   (M=2048, N=8192, K=2048)
    gemm_nt<0><<<dim3(8192 / 64, M_TOT / 64), blk, 0, stream>>>(
        x, D_MODEL, in_proj_w, xz, 8192, M_TOT, 2 * D_INNER, D_MODEL, nullptr);

    // 2) conv + silu -> xs ; also writes new_conv_cache
    conv_silu<<<dim3(TT / 128, D_INNER / 256, NB), blk, 0, stream>>>(
        xz, conv_cache, conv_w, conv_b, xs, cc_out);

    // 3) dbc = xs @ x_proj_w^T   (M=2048, N=160, K=4096)
    gemm_nt<0><<<dim3((160 + 63) / 64, M_TOT / 64), blk, 0, stream>>>(
        xs, D_INNER, x_proj_w, dbc, 160, M_TOT, DT_RANK + 2 * D_STATE, D_INNER, nullptr);

    // 4) delta = softplus(dbc[:, :128] @ dt_proj_w^T + b) -> xi region of xz (ldc=8192)
    gemm_nt<1><<<dim3(D_INNER / 64, M_TOT / 64), blk, 0, stream>>>(
        dbc, DT_RANK + 2 * D_STATE, dt_proj_w, xz, 8192, M_TOT, D_INNER, DT_RANK, dt_proj_b);

    // 5) selective scan; rewrites xs in-place with (y + D*xs)*silu(z); writes h_last
    scan_kernel<<<dim3(NB * D_INNER / 256), blk, 0, stream>>>(
        xz, dbc, xs, h_in, A_log, D_param, h_out);

    // 6) out = ygated @ out_proj_w^T   (M=2048, N=2048, K=4096)
    gemm_nt<0><<<dim3(D_MODEL / 64, M_TOT / 64), blk, 0, stream>>>(
        xs, D_INNER, out_proj_w, out, D_MODEL, M_TOT, D_MODEL, D_INNER, nullptr);
}

// Round 2
// 1309.360 us; speedup vs baseline: 2.3857x; 2.3857x over previous
//
#include <hip/hip_runtime.h>
#include <hip/hip_bf16.h>
#include <math.h>

#define D_MODEL 2048
#define D_INNER 4096
#define D_STATE 16
#define D_CONV  4
#define DT_RANK 128
#define NB      2
#define TT      1024
#define M_TOT   (NB * TT)          // 2048 rows for all GEMMs

typedef __bf16 bf16x8_t __attribute__((ext_vector_type(8)));
typedef float  f32x4_t  __attribute__((ext_vector_type(4)));

// ---------------------------------------------------------------------------
// fp32 -> bf16 cast, 8 elems/thread
// ---------------------------------------------------------------------------
__global__ __launch_bounds__(256) void cast_f32_bf16(
    const float* __restrict__ src, __bf16* __restrict__ dst, int n8)
{
    int i = blockIdx.x * 256 + threadIdx.x;
    if (i >= n8) return;
    const float4 f0 = ((const float4*)src)[2 * i];
    const float4 f1 = ((const float4*)src)[2 * i + 1];
    bf16x8_t v;
    v[0] = (__bf16)f0.x; v[1] = (__bf16)f0.y; v[2] = (__bf16)f0.z; v[3] = (__bf16)f0.w;
    v[4] = (__bf16)f1.x; v[5] = (__bf16)f1.y; v[6] = (__bf16)f1.z; v[7] = (__bf16)f1.w;
    ((bf16x8_t*)dst)[i] = v;
}

// ---------------------------------------------------------------------------
// bf16 MFMA GEMM: C(M,N) fp32 = A(M,K) bf16 @ W(N,K)^T bf16.
// 128x128 tile, BK=32, 256 threads (4 waves, each 64x64), m97 structure:
// global_load_lds dwordx4 staging + 2-barrier K-loop.
// M, N multiples of 128 (grid-exact), K multiple of 32. No bounds checks.
// ---------------------------------------------------------------------------
__global__ __launch_bounds__(256) void gemm_bf16_nt(
    const __bf16* __restrict__ A,
    const __bf16* __restrict__ W,
    float* __restrict__ C, int ldc, int K)
{
    __shared__ __bf16 As[128 * 32];   // 8 KB
    __shared__ __bf16 Bs[128 * 32];   // 8 KB

    const int tid  = threadIdx.x;
    const int wave = tid >> 6;
    const int lane = tid & 63;
    const int m0 = blockIdx.y * 128;
    const int n0 = blockIdx.x * 128;
    const int mw = (wave >> 1) * 64;
    const int nw = (wave & 1) * 64;

    f32x4_t acc[4][4] = {};

    // staging: wave w covers groups g0=2w, 2w+1 ; lane covers 16B = 8 bf16
    const int g0 = wave * 2;
    const int rA = g0 * 16 + (lane >> 2);      // row within 128-tile (group g0)
    const int kk = (lane & 3) * 8;             // k offset within BK=32

    const __bf16* gA0 = A + (size_t)(m0 + rA) * K + kk;
    const __bf16* gA1 = gA0 + (size_t)16 * K;
    const __bf16* gB0 = W + (size_t)(n0 + rA) * K + kk;
    const __bf16* gB1 = gB0 + (size_t)16 * K;

    __bf16* lA0 = &As[(size_t)g0 * 512];
    __bf16* lA1 = &As[(size_t)(g0 + 1) * 512];
    __bf16* lB0 = &Bs[(size_t)g0 * 512];
    __bf16* lB1 = &Bs[(size_t)(g0 + 1) * 512];

    const int fr = lane & 15;            // fragment row (m or n)
    const int fk = (lane >> 4) * 8;      // fragment k

    for (int k0 = 0; k0 < K; k0 += 32) {
        __builtin_amdgcn_global_load_lds(
            (const __attribute__((address_space(1))) void*)(gA0 + k0),
            (__attribute__((address_space(3))) void*)lA0, 16, 0, 0);
        __builtin_amdgcn_global_load_lds(
            (const __attribute__((address_space(1))) void*)(gA1 + k0),
            (__attribute__((address_space(3))) void*)lA1, 16, 0, 0);
        __builtin_amdgcn_global_load_lds(
            (const __attribute__((address_space(1))) void*)(gB0 + k0),
            (__attribute__((address_space(3))) void*)lB0, 16, 0, 0);
        __builtin_amdgcn_global_load_lds(
            (const __attribute__((address_space(1))) void*)(gB1 + k0),
            (__attribute__((address_space(3))) void*)lB1, 16, 0, 0);
        __syncthreads();   // compiler drains vmcnt before s_barrier

        bf16x8_t av[4], bv[4];
#pragma unroll
        for (int mt = 0; mt < 4; mt++)
            av[mt] = *(const bf16x8_t*)&As[(mw + mt * 16 + fr) * 32 + fk];
#pragma unroll
        for (int nt = 0; nt < 4; nt++)
            bv[nt] = *(const bf16x8_t*)&Bs[(nw + nt * 16 + fr) * 32 + fk];

#pragma unroll
        for (int mt = 0; mt < 4; mt++)
#pragma unroll
            for (int nt = 0; nt < 4; nt++)
                acc[mt][nt] = __builtin_amdgcn_mfma_f32_16x16x32_bf16(
                    av[mt], bv[nt], acc[mt][nt], 0, 0, 0);
        __syncthreads();   // all waves done reading LDS before next stage
    }

    // C/D layout: col = lane&15, row = (lane>>4)*4 + reg
    const int cn = n0 + nw + (lane & 15);
    const int rb = m0 + mw + (lane >> 4) * 4;
#pragma unroll
    for (int mt = 0; mt < 4; mt++)
#pragma unroll
        for (int nt = 0; nt < 4; nt++)
#pragma unroll
            for (int r = 0; r < 4; r++)
                C[(size_t)(rb + mt * 16 + r) * ldc + cn + nt * 16] = acc[mt][nt][r];
}

// ---------------------------------------------------------------------------
// fp32 GEMM C = A(M,K;lda) @ W(N,K)^T, tile 64x64x16, 256 thr, 4x4/thread.
// EPI: 0 = plain store, 1 = +bias then softplus, 2 = atomicAdd (split-K).
// Split-K via gridDim.z (K chunk = K/gridDim.z).
// ---------------------------------------------------------------------------
template <int EPI>
__global__ __launch_bounds__(256) void gemm_nt(
    const float* __restrict__ A, int lda,
    const float* __restrict__ W,
    float* __restrict__ C, int ldc,
    int M, int N, int K,
    const float* __restrict__ bias)
{
    __shared__ __align__(16) float As[16][68];
    __shared__ __align__(16) float Ws[16][68];

    const int tid = threadIdx.x;
    const int tx = tid & 15, ty = tid >> 4;
    const int m0 = blockIdx.y * 64, n0 = blockIdx.x * 64;
    const int lr = tid >> 4;
    const int lk = tid & 15;

    const int kc = K / gridDim.z;
    const int kb = blockIdx.z * kc;

    float acc[4][4] = {};

    for (int k0 = kb; k0 < kb + kc; k0 += 16) {
#pragma unroll
        for (int i = 0; i < 4; i++) {
            int m = m0 + lr + i * 16;
            As[lk][lr + i * 16] = (m < M) ? A[(size_t)m * lda + k0 + lk] : 0.f;
        }
#pragma unroll
        for (int i = 0; i < 4; i++) {
            int n = n0 + lr + i * 16;
            Ws[lk][lr + i * 16] = (n < N) ? W[(size_t)n * K + k0 + lk] : 0.f;
        }
        __syncthreads();
#pragma unroll
        for (int kkk = 0; kkk < 16; kkk++) {
            float a[4], b[4];
            *(float4*)a = *(const float4*)&As[kkk][ty * 4];
            *(float4*)b = *(const float4*)&Ws[kkk][tx * 4];
#pragma unroll
            for (int i = 0; i < 4; i++)
#pragma unroll
                for (int j = 0; j < 4; j++)
                    acc[i][j] += a[i] * b[j];
        }
        __syncthreads();
    }

#pragma unroll
    for (int i = 0; i < 4; i++) {
        int m = m0 + ty * 4 + i;
        if (m >= M) continue;
#pragma unroll
        for (int j = 0; j < 4; j++) {
            int n = n0 + tx * 4 + j;
            if (n >= N) continue;
            float v = acc[i][j];
            if (EPI == 1) {
                v += bias[n];
                v = (v > 20.f) ? v : log1pf(__expf(v));
            }
            if (EPI == 2) atomicAdd(&C[(size_t)m * ldc + n], v);
            else          C[(size_t)m * ldc + n] = v;
        }
    }
}

// ---------------------------------------------------------------------------
// Causal depthwise conv (width 4) + bias + silu, with history cache.
// ---------------------------------------------------------------------------
__global__ __launch_bounds__(256) void conv_silu(
    const float* __restrict__ xz,
    const float* __restrict__ conv_cache,
    const float* __restrict__ conv_w,
    const float* __restrict__ conv_b,
    float* __restrict__ xs,
    float* __restrict__ cc_out)
{
    const int b  = blockIdx.z;
    const int d  = blockIdx.y * 256 + threadIdx.x;
    const int t0 = blockIdx.x * 128;

    const float4 w  = *(const float4*)&conv_w[d * 4];
    const float bias = conv_b[d];

    float xm3, xm2, xm1;
    if (t0 == 0) {
        xm3 = conv_cache[(b * D_INNER + d) * 3 + 0];
        xm2 = conv_cache[(b * D_INNER + d) * 3 + 1];
        xm1 = conv_cache[(b * D_INNER + d) * 3 + 2];
    } else {
        xm3 = xz[(size_t)(b * TT + t0 - 3) * 8192 + d];
        xm2 = xz[(size_t)(b * TT + t0 - 2) * 8192 + d];
        xm1 = xz[(size_t)(b * TT + t0 - 1) * 8192 + d];
    }

    for (int t = t0; t < t0 + 128; t++) {
        float xc = xz[(size_t)(b * TT + t) * 8192 + d];
        float v  = xm3 * w.x + xm2 * w.y + xm1 * w.z + xc * w.w + bias;
        float s  = v / (1.f + __expf(-v));
        xs[(size_t)(b * TT + t) * 4096 + d] = s;
        xm3 = xm2; xm2 = xm1; xm1 = xc;
    }

    if (t0 + 128 == TT) {
        cc_out[(b * D_INNER + d) * 3 + 0] = xm3;
        cc_out[(b * D_INNER + d) * 3 + 1] = xm2;
        cc_out[(b * D_INNER + d) * 3 + 2] = xm1;
    }
}

// ---------------------------------------------------------------------------
// Selective scan: 4 lanes per (b,d), 4 states each, quad shfl-reduce for
// the C-dot.  Writes gated y directly as bf16 (out_proj input) + h_last.
// ---------------------------------------------------------------------------
__global__ __launch_bounds__(256) void scan_kernel(
    const float* __restrict__ xz,     // delta in cols 0:4096, z in 4096:8192
    const float* __restrict__ dbc,    // (2048,160): B at 128, C at 144
    const float* __restrict__ xs,
    const float* __restrict__ h_in,
    const float* __restrict__ A_log,
    const float* __restrict__ D_param,
    __bf16* __restrict__ ys16,        // (2048,4096) gated y, bf16
    float* __restrict__ h_out)
{
    const int idx  = blockIdx.x * 256 + threadIdx.x;   // 0..32767
    const int team = idx >> 2;
    const int sub  = idx & 3;
    const int b = team >> 12;
    const int d = team & 4095;

    const float4 Af = *(const float4*)&A_log[d * 16 + sub * 4];
    const float Ad0 = -__expf(Af.x), Ad1 = -__expf(Af.y);
    const float Ad2 = -__expf(Af.z), Ad3 = -__expf(Af.w);
    float4 hf = *(const float4*)&h_in[(size_t)(b * D_INNER + d) * 16 + sub * 4];
    float h0 = hf.x, h1 = hf.y, h2 = hf.z, h3 = hf.w;
    const float Dp = D_param[d];

    const float* pdelta = xz + (size_t)b * TT * 8192 + d;
    const float* pz     = pdelta + 4096;
    const float* px     = xs + (size_t)b * TT * 4096 + d;
    const float* pB     = dbc + (size_t)b * TT * 160 + 128 + sub * 4;
    const float* pC     = pB + 16;
    __bf16* py = ys16 + (size_t)b * TT * 4096 + d;

    for (int t = 0; t < TT; t++) {
        const float delta = pdelta[(size_t)t * 8192];
        const float xv    = px[(size_t)t * 4096];
        const float4 Bv = *(const float4*)&pB[(size_t)t * 160];
        const float4 Cv = *(const float4*)&pC[(size_t)t * 160];
        const float dx = delta * xv;

        h0 = __expf(delta * Ad0) * h0 + dx * Bv.x;
        h1 = __expf(delta * Ad1) * h1 + dx * Bv.y;
        h2 = __expf(delta * Ad2) * h2 + dx * Bv.z;
        h3 = __expf(delta * Ad3) * h3 + dx * Bv.w;

        float y = h0 * Cv.x + h1 * Cv.y + h2 * Cv.z + h3 * Cv.w;
        y += __shfl_xor(y, 1);
        y += __shfl_xor(y, 2);

        if (sub == 0) {
            const float zv = pz[(size_t)t * 8192];
            y += Dp * xv;
            const float g = zv / (1.f + __expf(-zv));
            py[(size_t)t * 4096] = (__bf16)(y * g);
        }
    }

    *(float4*)&h_out[(size_t)(b * D_INNER + d) * 16 + sub * 4] =
        make_float4(h0, h1, h2, h3);
}

// ---------------------------------------------------------------------------
extern "C" void kernel_launch(void* const* d_in, const int* in_sizes, int n_in,
                              void* d_out, int out_size, void* d_ws, size_t ws_size,
                              hipStream_t stream)
{
    const float* x          = (const float*)d_in[0];
    const float* h_in       = (const float*)d_in[1];
    const float* conv_cache = (const float*)d_in[2];
    const float* in_proj_w  = (const float*)d_in[3];
    const float* conv_w     = (const float*)d_in[4];
    const float* conv_b     = (const float*)d_in[5];
    const float* x_proj_w   = (const float*)d_in[6];
    const float* dt_proj_w  = (const float*)d_in[7];
    const float* dt_proj_b  = (const float*)d_in[8];
    const float* A_log      = (const float*)d_in[9];
    const float* D_param    = (const float*)d_in[10];
    const float* out_proj_w = (const float*)d_in[11];

    float* out    = (float*)d_out;
    float* h_out  = (float*)d_out + (size_t)NB * TT * D_MODEL;
    float* cc_out = h_out + (size_t)NB * D_INNER * D_STATE;

    char* ws = (char*)d_ws;
    // layout (with aliasing):
    //   [0, 64M)        xz fp32 (2048x8192); first 16M reused for wo16 after scan
    //   [64M, 72M)      x16 bf16 (2048x2048)          -- dead after in_proj
    //   [72M, 104M)     wi16 bf16 (8192x2048)         -- dead after in_proj
    //   [64M, 96M)      xs fp32 (2048x4096), written by conv AFTER in_proj
    //   [104M, ~105.3M) dbc fp32 (2048x160)
    //   [~105.3M, +16M) ys16 bf16 (2048x4096)
    float*  xz   = (float*)(ws);
    __bf16* x16  = (__bf16*)(ws + 67108864);
    __bf16* wi16 = (__bf16*)(ws + 75497472);
    float*  xs   = (float*)(ws + 67108864);          // aliases x16+wi16 (later)
    float*  dbc  = (float*)(ws + 109051904);
    __bf16* ys16 = (__bf16*)(ws + 110362624);
    __bf16* wo16 = (__bf16*)(ws);                    // aliases xz (after scan)

    dim3 blk(256);

    // 0) casts for in_proj
    cast_f32_bf16<<<dim3((D_MODEL * M_TOT / 8 + 255) / 256), blk, 0, stream>>>(
        x, x16, D_MODEL * M_TOT / 8);
    cast_f32_bf16<<<dim3((8192 * 2048 / 8 + 255) / 256), blk, 0, stream>>>(
        in_proj_w, wi16, 8192 * 2048 / 8);

    // 1) xz = x @ in_proj_w^T   (bf16 MFMA: M=2048, N=8192, K=2048)
    gemm_bf16_nt<<<dim3(8192 / 128, M_TOT / 128), blk, 0, stream>>>(
        x16, wi16, xz, 8192, D_MODEL);

    // 2) conv + silu -> xs ; writes new_conv_cache
    conv_silu<<<dim3(TT / 128, D_INNER / 256, NB), blk, 0, stream>>>(
        xz, conv_cache, conv_w, conv_b, xs, cc_out);

    // 3) dbc = xs @ x_proj_w^T  (fp32, split-K=8, atomic)
    hipMemsetAsync(dbc, 0, (size_t)M_TOT * 160 * 4, stream);
    gemm_nt<2><<<dim3((160 + 63) / 64, M_TOT / 64, 8), blk, 0, stream>>>(
        xs, D_INNER, x_proj_w, dbc, 160, M_TOT, DT_RANK + 2 * D_STATE, D_INNER, nullptr);

    // 4) delta = softplus(dbc[:, :128] @ dt_proj_w^T + b) -> xi region of xz
    gemm_nt<1><<<dim3(D_INNER / 64, M_TOT / 64, 1), blk, 0, stream>>>(
        dbc, DT_RANK + 2 * D_STATE, dt_proj_w, xz, 8192, M_TOT, D_INNER, DT_RANK, dt_proj_b);

    // 5) selective scan -> ys16 (bf16 gated y), h_out
    scan_kernel<<<dim3(NB * D_INNER * 4 / 256), blk, 0, stream>>>(
        xz, dbc, xs, h_in, A_log, D_param, ys16, h_out);

    // 6) cast out_proj_w (into dead xz region), then out = ys @ W^T (bf16 MFMA)
    cast_f32_bf16<<<dim3((2048 * 4096 / 8 + 255) / 256), blk, 0, stream>>>(
        out_proj_w, wo16, 2048 * 4096 / 8);
    gemm_bf16_nt<<<dim3(D_MODEL / 128, M_TOT / 128), blk, 0, stream>>>(
        ys16, wo16, out, D_MODEL, D_INNER);
}

// Round 3
// 687.500 us; speedup vs baseline: 4.5436x; 1.9045x over previous
//
#include <hip/hip_runtime.h>
#include <hip/hip_bf16.h>
#include <math.h>

#define D_MODEL 2048
#define D_INNER 4096
#define D_STATE 16
#define D_CONV  4
#define DT_RANK 128
#define NB      2
#define TT      1024
#define M_TOT   (NB * TT)          // 2048 rows for all GEMMs
#define NC      16                 // scan chunks
#define CL      64                 // chunk length (TT/NC)

typedef __bf16 bf16x8_t __attribute__((ext_vector_type(8)));
typedef float  f32x4_t  __attribute__((ext_vector_type(4)));

// ---------------------------------------------------------------------------
// fp32 -> bf16 cast, 8 elems/thread
// ---------------------------------------------------------------------------
__global__ __launch_bounds__(256) void cast_f32_bf16(
    const float* __restrict__ src, __bf16* __restrict__ dst, int n8)
{
    int i = blockIdx.x * 256 + threadIdx.x;
    if (i >= n8) return;
    const float4 f0 = ((const float4*)src)[2 * i];
    const float4 f1 = ((const float4*)src)[2 * i + 1];
    bf16x8_t v;
    v[0] = (__bf16)f0.x; v[1] = (__bf16)f0.y; v[2] = (__bf16)f0.z; v[3] = (__bf16)f0.w;
    v[4] = (__bf16)f1.x; v[5] = (__bf16)f1.y; v[6] = (__bf16)f1.z; v[7] = (__bf16)f1.w;
    ((bf16x8_t*)dst)[i] = v;
}

// ---------------------------------------------------------------------------
// bf16 MFMA GEMM: C(M,N) fp32 = A(M,K) bf16 @ W(N,K)^T bf16.
// 128x128 tile, BK=32, 256 threads (4 waves, each 64x64), m97 structure.
// ---------------------------------------------------------------------------
__global__ __launch_bounds__(256) void gemm_bf16_nt(
    const __bf16* __restrict__ A,
    const __bf16* __restrict__ W,
    float* __restrict__ C, int ldc, int K)
{
    __shared__ __bf16 As[128 * 32];
    __shared__ __bf16 Bs[128 * 32];

    const int tid  = threadIdx.x;
    const int wave = tid >> 6;
    const int lane = tid & 63;
    const int m0 = blockIdx.y * 128;
    const int n0 = blockIdx.x * 128;
    const int mw = (wave >> 1) * 64;
    const int nw = (wave & 1) * 64;

    f32x4_t acc[4][4] = {};

    const int g0 = wave * 2;
    const int rA = g0 * 16 + (lane >> 2);
    const int kk = (lane & 3) * 8;

    const __bf16* gA0 = A + (size_t)(m0 + rA) * K + kk;
    const __bf16* gA1 = gA0 + (size_t)16 * K;
    const __bf16* gB0 = W + (size_t)(n0 + rA) * K + kk;
    const __bf16* gB1 = gB0 + (size_t)16 * K;

    __bf16* lA0 = &As[(size_t)g0 * 512];
    __bf16* lA1 = &As[(size_t)(g0 + 1) * 512];
    __bf16* lB0 = &Bs[(size_t)g0 * 512];
    __bf16* lB1 = &Bs[(size_t)(g0 + 1) * 512];

    const int fr = lane & 15;
    const int fk = (lane >> 4) * 8;

    for (int k0 = 0; k0 < K; k0 += 32) {
        __builtin_amdgcn_global_load_lds(
            (const __attribute__((address_space(1))) void*)(gA0 + k0),
            (__attribute__((address_space(3))) void*)lA0, 16, 0, 0);
        __builtin_amdgcn_global_load_lds(
            (const __attribute__((address_space(1))) void*)(gA1 + k0),
            (__attribute__((address_space(3))) void*)lA1, 16, 0, 0);
        __builtin_amdgcn_global_load_lds(
            (const __attribute__((address_space(1))) void*)(gB0 + k0),
            (__attribute__((address_space(3))) void*)lB0, 16, 0, 0);
        __builtin_amdgcn_global_load_lds(
            (const __attribute__((address_space(1))) void*)(gB1 + k0),
            (__attribute__((address_space(3))) void*)lB1, 16, 0, 0);
        __syncthreads();

        bf16x8_t av[4], bv[4];
#pragma unroll
        for (int mt = 0; mt < 4; mt++)
            av[mt] = *(const bf16x8_t*)&As[(mw + mt * 16 + fr) * 32 + fk];
#pragma unroll
        for (int nt = 0; nt < 4; nt++)
            bv[nt] = *(const bf16x8_t*)&Bs[(nw + nt * 16 + fr) * 32 + fk];

#pragma unroll
        for (int mt = 0; mt < 4; mt++)
#pragma unroll
            for (int nt = 0; nt < 4; nt++)
                acc[mt][nt] = __builtin_amdgcn_mfma_f32_16x16x32_bf16(
                    av[mt], bv[nt], acc[mt][nt], 0, 0, 0);
        __syncthreads();
    }

    const int cn = n0 + nw + (lane & 15);
    const int rb = m0 + mw + (lane >> 4) * 4;
#pragma unroll
    for (int mt = 0; mt < 4; mt++)
#pragma unroll
        for (int nt = 0; nt < 4; nt++)
#pragma unroll
            for (int r = 0; r < 4; r++)
                C[(size_t)(rb + mt * 16 + r) * ldc + cn + nt * 16] = acc[mt][nt][r];
}

// ---------------------------------------------------------------------------
// fp32 GEMM C = A(M,K;lda) @ W(N,K)^T, tile 64x64x16.
// EPI: 0 plain, 1 +bias softplus, 2 atomicAdd (split-K via gridDim.z).
// ---------------------------------------------------------------------------
template <int EPI>
__global__ __launch_bounds__(256) void gemm_nt(
    const float* __restrict__ A, int lda,
    const float* __restrict__ W,
    float* __restrict__ C, int ldc,
    int M, int N, int K,
    const float* __restrict__ bias)
{
    __shared__ __align__(16) float As[16][68];
    __shared__ __align__(16) float Ws[16][68];

    const int tid = threadIdx.x;
    const int tx = tid & 15, ty = tid >> 4;
    const int m0 = blockIdx.y * 64, n0 = blockIdx.x * 64;
    const int lr = tid >> 4;
    const int lk = tid & 15;

    const int kc = K / gridDim.z;
    const int kb = blockIdx.z * kc;

    float acc[4][4] = {};

    for (int k0 = kb; k0 < kb + kc; k0 += 16) {
#pragma unroll
        for (int i = 0; i < 4; i++) {
            int m = m0 + lr + i * 16;
            As[lk][lr + i * 16] = (m < M) ? A[(size_t)m * lda + k0 + lk] : 0.f;
        }
#pragma unroll
        for (int i = 0; i < 4; i++) {
            int n = n0 + lr + i * 16;
            Ws[lk][lr + i * 16] = (n < N) ? W[(size_t)n * K + k0 + lk] : 0.f;
        }
        __syncthreads();
#pragma unroll
        for (int kkk = 0; kkk < 16; kkk++) {
            float a[4], b[4];
            *(float4*)a = *(const float4*)&As[kkk][ty * 4];
            *(float4*)b = *(const float4*)&Ws[kkk][tx * 4];
#pragma unroll
            for (int i = 0; i < 4; i++)
#pragma unroll
                for (int j = 0; j < 4; j++)
                    acc[i][j] += a[i] * b[j];
        }
        __syncthreads();
    }

#pragma unroll
    for (int i = 0; i < 4; i++) {
        int m = m0 + ty * 4 + i;
        if (m >= M) continue;
#pragma unroll
        for (int j = 0; j < 4; j++) {
            int n = n0 + tx * 4 + j;
            if (n >= N) continue;
            float v = acc[i][j];
            if (EPI == 1) {
                v += bias[n];
                v = (v > 20.f) ? v : log1pf(__expf(v));
            }
            if (EPI == 2) atomicAdd(&C[(size_t)m * ldc + n], v);
            else          C[(size_t)m * ldc + n] = v;
        }
    }
}

// ---------------------------------------------------------------------------
// Causal depthwise conv (width 4) + bias + silu, with history cache.
// ---------------------------------------------------------------------------
__global__ __launch_bounds__(256) void conv_silu(
    const float* __restrict__ xz,
    const float* __restrict__ conv_cache,
    const float* __restrict__ conv_w,
    const float* __restrict__ conv_b,
    float* __restrict__ xs,
    float* __restrict__ cc_out)
{
    const int b  = blockIdx.z;
    const int d  = blockIdx.y * 256 + threadIdx.x;
    const int t0 = blockIdx.x * 128;

    const float4 w  = *(const float4*)&conv_w[d * 4];
    const float bias = conv_b[d];

    float xm3, xm2, xm1;
    if (t0 == 0) {
        xm3 = conv_cache[(b * D_INNER + d) * 3 + 0];
        xm2 = conv_cache[(b * D_INNER + d) * 3 + 1];
        xm1 = conv_cache[(b * D_INNER + d) * 3 + 2];
    } else {
        xm3 = xz[(size_t)(b * TT + t0 - 3) * 8192 + d];
        xm2 = xz[(size_t)(b * TT + t0 - 2) * 8192 + d];
        xm1 = xz[(size_t)(b * TT + t0 - 1) * 8192 + d];
    }

    for (int t = t0; t < t0 + 128; t++) {
        float xc = xz[(size_t)(b * TT + t) * 8192 + d];
        float v  = xm3 * w.x + xm2 * w.y + xm1 * w.z + xc * w.w + bias;
        float s  = v / (1.f + __expf(-v));
        xs[(size_t)(b * TT + t) * 4096 + d] = s;
        xm3 = xm2; xm2 = xm1; xm1 = xc;
    }

    if (t0 + 128 == TT) {
        cc_out[(b * D_INNER + d) * 3 + 0] = xm3;
        cc_out[(b * D_INNER + d) * 3 + 1] = xm2;
        cc_out[(b * D_INNER + d) * 3 + 2] = xm1;
    }
}

// ---------------------------------------------------------------------------
// Chunked selective scan.
// Thread decode (phases A/C): sub=idx&3 (4 states each), d=(idx>>2)&4095,
// c=(idx>>14)&15, b=idx>>18.  P/S layout: ((b*NC+c)*4096+d)*16+n.
// ---------------------------------------------------------------------------
// Phase A: per-chunk local scan from h=0 -> S; chunk decay P=exp(Ad*sum_delta).
__global__ __launch_bounds__(256) void scan_phase_a(
    const float* __restrict__ xz,     // delta at cols 0:4096 (ld 8192)
    const float* __restrict__ dbc,    // (2048,160): B at 128
    const float* __restrict__ xs,
    const float* __restrict__ A_log,
    float* __restrict__ P,
    float* __restrict__ S)
{
    const int idx = blockIdx.x * 256 + threadIdx.x;
    const int sub = idx & 3;
    const int d   = (idx >> 2) & 4095;
    const int c   = (idx >> 14) & (NC - 1);
    const int b   = idx >> 18;

    const float4 Af = *(const float4*)&A_log[d * 16 + sub * 4];
    const float Ad0 = -__expf(Af.x), Ad1 = -__expf(Af.y);
    const float Ad2 = -__expf(Af.z), Ad3 = -__expf(Af.w);

    const int t0 = c * CL;
    const float* pdelta = xz + (size_t)b * TT * 8192 + (size_t)t0 * 8192 + d;
    const float* px     = xs + (size_t)b * TT * 4096 + (size_t)t0 * 4096 + d;
    const float* pB     = dbc + ((size_t)b * TT + t0) * 160 + 128 + sub * 4;

    float h0 = 0.f, h1 = 0.f, h2 = 0.f, h3 = 0.f, sd = 0.f;
    for (int t = 0; t < CL; t++) {
        const float delta = pdelta[(size_t)t * 8192];
        const float xv    = px[(size_t)t * 4096];
        const float4 Bv   = *(const float4*)&pB[(size_t)t * 160];
        const float dx = delta * xv;
        h0 = __expf(delta * Ad0) * h0 + dx * Bv.x;
        h1 = __expf(delta * Ad1) * h1 + dx * Bv.y;
        h2 = __expf(delta * Ad2) * h2 + dx * Bv.z;
        h3 = __expf(delta * Ad3) * h3 + dx * Bv.w;
        sd += delta;
    }
    const size_t o = ((size_t)(b * NC + c) * 4096 + d) * 16 + sub * 4;
    *(float4*)&P[o] = make_float4(__expf(Ad0 * sd), __expf(Ad1 * sd),
                                  __expf(Ad2 * sd), __expf(Ad3 * sd));
    *(float4*)&S[o] = make_float4(h0, h1, h2, h3);
}

// Phase B: sequential chunk combine; rewrites P[c] with h_start[c]; h_out.
__global__ __launch_bounds__(256) void scan_phase_b(
    float* __restrict__ P,            // in: decay; out: h_start
    const float* __restrict__ S,
    const float* __restrict__ h_in,
    float* __restrict__ h_out)
{
    const int idx = blockIdx.x * 256 + threadIdx.x;   // 131072
    const int n = idx & 15;
    const int d = (idx >> 4) & 4095;
    const int b = idx >> 16;

    float h = h_in[((size_t)b * 4096 + d) * 16 + n];
#pragma unroll
    for (int c = 0; c < NC; c++) {
        const size_t o = ((size_t)(b * NC + c) * 4096 + d) * 16 + n;
        const float p = P[o], s = S[o];
        P[o] = h;                 // h_start for chunk c
        h = p * h + s;
    }
    h_out[((size_t)b * 4096 + d) * 16 + n] = h;
}

// Phase C: re-run chunk scans from h_start, emit gated y (bf16).
__global__ __launch_bounds__(256) void scan_phase_c(
    const float* __restrict__ xz,     // delta 0:4096, z 4096:8192
    const float* __restrict__ dbc,    // B at 128, C at 144
    const float* __restrict__ xs,
    const float* __restrict__ Hs,     // h_start (the rewritten P)
    const float* __restrict__ A_log,
    const float* __restrict__ D_param,
    __bf16* __restrict__ ys16)
{
    const int idx = blockIdx.x * 256 + threadIdx.x;
    const int sub = idx & 3;
    const int d   = (idx >> 2) & 4095;
    const int c   = (idx >> 14) & (NC - 1);
    const int b   = idx >> 18;

    const float4 Af = *(const float4*)&A_log[d * 16 + sub * 4];
    const float Ad0 = -__expf(Af.x), Ad1 = -__expf(Af.y);
    const float Ad2 = -__expf(Af.z), Ad3 = -__expf(Af.w);
    const float Dp = D_param[d];

    const size_t o = ((size_t)(b * NC + c) * 4096 + d) * 16 + sub * 4;
    float4 hf = *(const float4*)&Hs[o];
    float h0 = hf.x, h1 = hf.y, h2 = hf.z, h3 = hf.w;

    const int t0 = c * CL;
    const float* pdelta = xz + (size_t)b * TT * 8192 + (size_t)t0 * 8192 + d;
    const float* pz     = pdelta + 4096;
    const float* px     = xs + (size_t)b * TT * 4096 + (size_t)t0 * 4096 + d;
    const float* pB     = dbc + ((size_t)b * TT + t0) * 160 + 128 + sub * 4;
    const float* pC     = pB + 16;
    __bf16* py = ys16 + (size_t)b * TT * 4096 + (size_t)t0 * 4096 + d;

    for (int t = 0; t < CL; t++) {
        const float delta = pdelta[(size_t)t * 8192];
        const float xv    = px[(size_t)t * 4096];
        const float4 Bv   = *(const float4*)&pB[(size_t)t * 160];
        const float4 Cv   = *(const float4*)&pC[(size_t)t * 160];
        const float dx = delta * xv;

        h0 = __expf(delta * Ad0) * h0 + dx * Bv.x;
        h1 = __expf(delta * Ad1) * h1 + dx * Bv.y;
        h2 = __expf(delta * Ad2) * h2 + dx * Bv.z;
        h3 = __expf(delta * Ad3) * h3 + dx * Bv.w;

        float y = h0 * Cv.x + h1 * Cv.y + h2 * Cv.z + h3 * Cv.w;
        y += __shfl_xor(y, 1);
        y += __shfl_xor(y, 2);

        if (sub == 0) {
            const float zv = pz[(size_t)t * 8192];
            y += Dp * xv;
            const float g = zv / (1.f + __expf(-zv));
            py[(size_t)t * 4096] = (__bf16)(y * g);
        }
    }
}

// ---------------------------------------------------------------------------
extern "C" void kernel_launch(void* const* d_in, const int* in_sizes, int n_in,
                              void* d_out, int out_size, void* d_ws, size_t ws_size,
                              hipStream_t stream)
{
    const float* x          = (const float*)d_in[0];
    const float* h_in       = (const float*)d_in[1];
    const float* conv_cache = (const float*)d_in[2];
    const float* in_proj_w  = (const float*)d_in[3];
    const float* conv_w     = (const float*)d_in[4];
    const float* conv_b     = (const float*)d_in[5];
    const float* x_proj_w   = (const float*)d_in[6];
    const float* dt_proj_w  = (const float*)d_in[7];
    const float* dt_proj_b  = (const float*)d_in[8];
    const float* A_log      = (const float*)d_in[9];
    const float* D_param    = (const float*)d_in[10];
    const float* out_proj_w = (const float*)d_in[11];

    float* out    = (float*)d_out;
    float* h_out  = (float*)d_out + (size_t)NB * TT * D_MODEL;
    float* cc_out = h_out + (size_t)NB * D_INNER * D_STATE;

    // P/S scratch lives in the (dead until final GEMM) `out` region:
    // P = out[0 : 2^21), S = out[2^21 : 2^22).  16.78 MB = exactly out's size.
    float* Pbuf = out;
    float* Sbuf = out + 2097152;

    char* ws = (char*)d_ws;
    float*  xz   = (float*)(ws);                     // 64 MB (2048x8192)
    __bf16* x16  = (__bf16*)(ws + 67108864);
    __bf16* wi16 = (__bf16*)(ws + 75497472);
    float*  xs   = (float*)(ws + 67108864);          // aliases x16+wi16 (later)
    float*  dbc  = (float*)(ws + 109051904);
    __bf16* ys16 = (__bf16*)(ws + 110362624);
    __bf16* wo16 = (__bf16*)(ws);                    // aliases xz (after scan)

    dim3 blk(256);

    // 0) casts for in_proj
    cast_f32_bf16<<<dim3((D_MODEL * M_TOT / 8 + 255) / 256), blk, 0, stream>>>(
        x, x16, D_MODEL * M_TOT / 8);
    cast_f32_bf16<<<dim3((8192 * 2048 / 8 + 255) / 256), blk, 0, stream>>>(
        in_proj_w, wi16, 8192 * 2048 / 8);

    // 1) xz = x @ in_proj_w^T   (bf16 MFMA: M=2048, N=8192, K=2048)
    gemm_bf16_nt<<<dim3(8192 / 128, M_TOT / 128), blk, 0, stream>>>(
        x16, wi16, xz, 8192, D_MODEL);

    // 2) conv + silu -> xs ; writes new_conv_cache
    conv_silu<<<dim3(TT / 128, D_INNER / 256, NB), blk, 0, stream>>>(
        xz, conv_cache, conv_w, conv_b, xs, cc_out);

    // 3) dbc = xs @ x_proj_w^T  (fp32, split-K=8, atomic)
    hipMemsetAsync(dbc, 0, (size_t)M_TOT * 160 * 4, stream);
    gemm_nt<2><<<dim3((160 + 63) / 64, M_TOT / 64, 8), blk, 0, stream>>>(
        xs, D_INNER, x_proj_w, dbc, 160, M_TOT, DT_RANK + 2 * D_STATE, D_INNER, nullptr);

    // 4) delta = softplus(dbc[:, :128] @ dt_proj_w^T + b) -> xi region of xz
    gemm_nt<1><<<dim3(D_INNER / 64, M_TOT / 64, 1), blk, 0, stream>>>(
        dbc, DT_RANK + 2 * D_STATE, dt_proj_w, xz, 8192, M_TOT, D_INNER, DT_RANK, dt_proj_b);

    // 5) chunked selective scan -> ys16 + h_out
    scan_phase_a<<<dim3(NB * D_INNER * NC * 4 / 256), blk, 0, stream>>>(
        xz, dbc, xs, A_log, Pbuf, Sbuf);
    scan_phase_b<<<dim3(NB * D_INNER * D_STATE / 256), blk, 0, stream>>>(
        Pbuf, Sbuf, h_in, h_out);
    scan_phase_c<<<dim3(NB * D_INNER * NC * 4 / 256), blk, 0, stream>>>(
        xz, dbc, xs, Pbuf, A_log, D_param, ys16);

    // 6) cast out_proj_w (into dead xz region), then out = ys @ W^T (bf16 MFMA)
    cast_f32_bf16<<<dim3((2048 * 4096 / 8 + 255) / 256), blk, 0, stream>>>(
        out_proj_w, wo16, 2048 * 4096 / 8);
    gemm_bf16_nt<<<dim3(D_MODEL / 128, M_TOT / 128), blk, 0, stream>>>(
        ys16, wo16, out, D_MODEL, D_INNER);
}

// Round 4
// 543.177 us; speedup vs baseline: 5.7508x; 1.2657x over previous
//
#include <hip/hip_runtime.h>
#include <hip/hip_bf16.h>
#include <math.h>

#define D_MODEL 2048
#define D_INNER 4096
#define D_STATE 16
#define D_CONV  4
#define DT_RANK 128
#define NB      2
#define TT      1024
#define M_TOT   (NB * TT)          // 2048 rows for all GEMMs
#define NC      16                 // scan chunks
#define CL      64                 // chunk length (TT/NC)
#define TC      16                 // conv t-chunk

typedef __bf16 bf16x8_t __attribute__((ext_vector_type(8)));
typedef float  f32x4_t  __attribute__((ext_vector_type(4)));

// ---------------------------------------------------------------------------
// fp32 -> bf16 cast, 8 elems/thread
// ---------------------------------------------------------------------------
__global__ __launch_bounds__(256) void cast_f32_bf16(
    const float* __restrict__ src, __bf16* __restrict__ dst, int n8)
{
    int i = blockIdx.x * 256 + threadIdx.x;
    if (i >= n8) return;
    const float4 f0 = ((const float4*)src)[2 * i];
    const float4 f1 = ((const float4*)src)[2 * i + 1];
    bf16x8_t v;
    v[0] = (__bf16)f0.x; v[1] = (__bf16)f0.y; v[2] = (__bf16)f0.z; v[3] = (__bf16)f0.w;
    v[4] = (__bf16)f1.x; v[5] = (__bf16)f1.y; v[6] = (__bf16)f1.z; v[7] = (__bf16)f1.w;
    ((bf16x8_t*)dst)[i] = v;
}

// dbc (2048x160) cols 0:128 -> dt16 (2048x128) bf16.  32768 threads.
__global__ __launch_bounds__(256) void cast_dt16(
    const float* __restrict__ dbc, __bf16* __restrict__ dt16)
{
    int i = blockIdx.x * 256 + threadIdx.x;   // 0..32767
    int row = i >> 4, chunk = i & 15;
    const float* s = dbc + (size_t)row * 160 + chunk * 8;
    const float4 f0 = *(const float4*)s;
    const float4 f1 = *(const float4*)(s + 4);
    bf16x8_t v;
    v[0] = (__bf16)f0.x; v[1] = (__bf16)f0.y; v[2] = (__bf16)f0.z; v[3] = (__bf16)f0.w;
    v[4] = (__bf16)f1.x; v[5] = (__bf16)f1.y; v[6] = (__bf16)f1.z; v[7] = (__bf16)f1.w;
    ((bf16x8_t*)(dt16 + (size_t)row * 128))[chunk] = v;
}

// ---------------------------------------------------------------------------
// bf16 MFMA GEMM: C(M,Nmax) fp32 (+EPI) = A(M,K;lda) bf16 @ W(N,K;ldw)^T.
// 128x128 tile, BK=32, 256 threads (4 waves), m97 structure.
// Split-K via gridDim.z (koff = z*Kloop).  EPI: 0 store, 1 +bias softplus,
// 2 atomicAdd.  Column guard n < Nmax (rows must be multiple of 128).
// ---------------------------------------------------------------------------
template <int EPI>
__global__ __launch_bounds__(256) void gemm_bf16_nt(
    const __bf16* __restrict__ A, int lda,
    const __bf16* __restrict__ W, int ldw,
    float* __restrict__ C, int ldc,
    int Kloop, int Nmax, const float* __restrict__ bias)
{
    __shared__ __bf16 As[128 * 32];
    __shared__ __bf16 Bs[128 * 32];

    const int tid  = threadIdx.x;
    const int wave = tid >> 6;
    const int lane = tid & 63;
    const int m0 = blockIdx.y * 128;
    const int n0 = blockIdx.x * 128;
    const int mw = (wave >> 1) * 64;
    const int nw = (wave & 1) * 64;
    const int koff = blockIdx.z * Kloop;

    f32x4_t acc[4][4] = {};

    const int g0 = wave * 2;
    const int rA = g0 * 16 + (lane >> 2);
    const int kk = (lane & 3) * 8;

    const __bf16* gA0 = A + (size_t)(m0 + rA) * lda + kk + koff;
    const __bf16* gA1 = gA0 + (size_t)16 * lda;
    const __bf16* gB0 = W + (size_t)(n0 + rA) * ldw + kk + koff;
    const __bf16* gB1 = gB0 + (size_t)16 * ldw;

    __bf16* lA0 = &As[(size_t)g0 * 512];
    __bf16* lA1 = &As[(size_t)(g0 + 1) * 512];
    __bf16* lB0 = &Bs[(size_t)g0 * 512];
    __bf16* lB1 = &Bs[(size_t)(g0 + 1) * 512];

    const int fr = lane & 15;
    const int fk = (lane >> 4) * 8;

    for (int k0 = 0; k0 < Kloop; k0 += 32) {
        __builtin_amdgcn_global_load_lds(
            (const __attribute__((address_space(1))) void*)(gA0 + k0),
            (__attribute__((address_space(3))) void*)lA0, 16, 0, 0);
        __builtin_amdgcn_global_load_lds(
            (const __attribute__((address_space(1))) void*)(gA1 + k0),
            (__attribute__((address_space(3))) void*)lA1, 16, 0, 0);
        __builtin_amdgcn_global_load_lds(
            (const __attribute__((address_space(1))) void*)(gB0 + k0),
            (__attribute__((address_space(3))) void*)lB0, 16, 0, 0);
        __builtin_amdgcn_global_load_lds(
            (const __attribute__((address_space(1))) void*)(gB1 + k0),
            (__attribute__((address_space(3))) void*)lB1, 16, 0, 0);
        __syncthreads();

        bf16x8_t av[4], bv[4];
#pragma unroll
        for (int mt = 0; mt < 4; mt++)
            av[mt] = *(const bf16x8_t*)&As[(mw + mt * 16 + fr) * 32 + fk];
#pragma unroll
        for (int nt = 0; nt < 4; nt++)
            bv[nt] = *(const bf16x8_t*)&Bs[(nw + nt * 16 + fr) * 32 + fk];

#pragma unroll
        for (int mt = 0; mt < 4; mt++)
#pragma unroll
            for (int nt = 0; nt < 4; nt++)
                acc[mt][nt] = __builtin_amdgcn_mfma_f32_16x16x32_bf16(
                    av[mt], bv[nt], acc[mt][nt], 0, 0, 0);
        __syncthreads();
    }

    // C/D layout: col = lane&15, row = (lane>>4)*4 + reg
    const int cn = n0 + nw + (lane & 15);
    const int rb = m0 + mw + (lane >> 4) * 4;
#pragma unroll
    for (int mt = 0; mt < 4; mt++)
#pragma unroll
        for (int nt = 0; nt < 4; nt++) {
            const int n = cn + nt * 16;
            if (n >= Nmax) continue;
#pragma unroll
            for (int r = 0; r < 4; r++) {
                float v = acc[mt][nt][r];
                float* p = &C[(size_t)(rb + mt * 16 + r) * ldc + n];
                if (EPI == 1) {
                    v += bias[n];
                    v = (v > 20.f) ? v : log1pf(__expf(v));
                    *p = v;
                } else if (EPI == 2) {
                    atomicAdd(p, v);
                } else {
                    *p = v;
                }
            }
        }
}

// ---------------------------------------------------------------------------
// Causal depthwise conv (width 4) + bias + silu, t-chunk TC per thread.
// Emits xs fp32 + xs16 bf16 + new_conv_cache.  grid (TT/TC, D_INNER/256, B).
// ---------------------------------------------------------------------------
__global__ __launch_bounds__(256) void conv_silu(
    const float* __restrict__ xz,
    const float* __restrict__ conv_cache,
    const float* __restrict__ conv_w,
    const float* __restrict__ conv_b,
    float* __restrict__ xs,
    __bf16* __restrict__ xs16,
    float* __restrict__ cc_out)
{
    const int b  = blockIdx.z;
    const int d  = blockIdx.y * 256 + threadIdx.x;
    const int t0 = blockIdx.x * TC;

    const float4 w  = *(const float4*)&conv_w[d * 4];
    const float bias = conv_b[d];

    float v[TC + 3];
    if (t0 == 0) {
        v[0] = conv_cache[(b * D_INNER + d) * 3 + 0];
        v[1] = conv_cache[(b * D_INNER + d) * 3 + 1];
        v[2] = conv_cache[(b * D_INNER + d) * 3 + 2];
    } else {
        v[0] = xz[(size_t)(b * TT + t0 - 3) * 8192 + d];
        v[1] = xz[(size_t)(b * TT + t0 - 2) * 8192 + d];
        v[2] = xz[(size_t)(b * TT + t0 - 1) * 8192 + d];
    }
#pragma unroll
    for (int k = 0; k < TC; k++)
        v[k + 3] = xz[(size_t)(b * TT + t0 + k) * 8192 + d];

#pragma unroll
    for (int k = 0; k < TC; k++) {
        float c = v[k] * w.x + v[k + 1] * w.y + v[k + 2] * w.z + v[k + 3] * w.w + bias;
        float s = c / (1.f + __expf(-c));
        const size_t o = (size_t)(b * TT + t0 + k) * 4096 + d;
        xs[o] = s;
        xs16[o] = (__bf16)s;
    }

    if (t0 + TC == TT) {
        cc_out[(b * D_INNER + d) * 3 + 0] = v[TC];
        cc_out[(b * D_INNER + d) * 3 + 1] = v[TC + 1];
        cc_out[(b * D_INNER + d) * 3 + 2] = v[TC + 2];
    }
}

// ---------------------------------------------------------------------------
// Chunked selective scan (3 phases).  P/S layout: ((b*NC+c)*4096+d)*16+n.
// ---------------------------------------------------------------------------
__global__ __launch_bounds__(256) void scan_phase_a(
    const float* __restrict__ xz,     // delta at cols 0:4096 (ld 8192)
    const float* __restrict__ dbc,    // (2048,160): B at 128
    const float* __restrict__ xs,
    const float* __restrict__ A_log,
    float* __restrict__ P,
    float* __restrict__ S)
{
    const int idx = blockIdx.x * 256 + threadIdx.x;
    const int sub = idx & 3;
    const int d   = (idx >> 2) & 4095;
    const int c   = (idx >> 14) & (NC - 1);
    const int b   = idx >> 18;

    const float4 Af = *(const float4*)&A_log[d * 16 + sub * 4];
    const float Ad0 = -__expf(Af.x), Ad1 = -__expf(Af.y);
    const float Ad2 = -__expf(Af.z), Ad3 = -__expf(Af.w);

    const int t0 = c * CL;
    const float* pdelta = xz + (size_t)b * TT * 8192 + (size_t)t0 * 8192 + d;
    const float* px     = xs + (size_t)b * TT * 4096 + (size_t)t0 * 4096 + d;
    const float* pB     = dbc + ((size_t)b * TT + t0) * 160 + 128 + sub * 4;

    float h0 = 0.f, h1 = 0.f, h2 = 0.f, h3 = 0.f, sd = 0.f;
    for (int t = 0; t < CL; t++) {
        const float delta = pdelta[(size_t)t * 8192];
        const float xv    = px[(size_t)t * 4096];
        const float4 Bv   = *(const float4*)&pB[(size_t)t * 160];
        const float dx = delta * xv;
        h0 = __expf(delta * Ad0) * h0 + dx * Bv.x;
        h1 = __expf(delta * Ad1) * h1 + dx * Bv.y;
        h2 = __expf(delta * Ad2) * h2 + dx * Bv.z;
        h3 = __expf(delta * Ad3) * h3 + dx * Bv.w;
        sd += delta;
    }
    const size_t o = ((size_t)(b * NC + c) * 4096 + d) * 16 + sub * 4;
    *(float4*)&P[o] = make_float4(__expf(Ad0 * sd), __expf(Ad1 * sd),
                                  __expf(Ad2 * sd), __expf(Ad3 * sd));
    *(float4*)&S[o] = make_float4(h0, h1, h2, h3);
}

__global__ __launch_bounds__(256) void scan_phase_b(
    float* __restrict__ P,            // in: decay; out: h_start
    const float* __restrict__ S,
    const float* __restrict__ h_in,
    float* __restrict__ h_out)
{
    const int idx = blockIdx.x * 256 + threadIdx.x;   // 131072
    const int n = idx & 15;
    const int d = (idx >> 4) & 4095;
    const int b = idx >> 16;

    float h = h_in[((size_t)b * 4096 + d) * 16 + n];
#pragma unroll
    for (int c = 0; c < NC; c++) {
        const size_t o = ((size_t)(b * NC + c) * 4096 + d) * 16 + n;
        const float p = P[o], s = S[o];
        P[o] = h;
        h = p * h + s;
    }
    h_out[((size_t)b * 4096 + d) * 16 + n] = h;
}

__global__ __launch_bounds__(256) void scan_phase_c(
    const float* __restrict__ xz,     // delta 0:4096, z 4096:8192
    const float* __restrict__ dbc,    // B at 128, C at 144
    const float* __restrict__ xs,
    const float* __restrict__ Hs,     // h_start (the rewritten P)
    const float* __restrict__ A_log,
    const float* __restrict__ D_param,
    __bf16* __restrict__ ys16)
{
    const int idx = blockIdx.x * 256 + threadIdx.x;
    const int sub = idx & 3;
    const int d   = (idx >> 2) & 4095;
    const int c   = (idx >> 14) & (NC - 1);
    const int b   = idx >> 18;

    const float4 Af = *(const float4*)&A_log[d * 16 + sub * 4];
    const float Ad0 = -__expf(Af.x), Ad1 = -__expf(Af.y);
    const float Ad2 = -__expf(Af.z), Ad3 = -__expf(Af.w);
    const float Dp = D_param[d];

    const size_t o = ((size_t)(b * NC + c) * 4096 + d) * 16 + sub * 4;
    float4 hf = *(const float4*)&Hs[o];
    float h0 = hf.x, h1 = hf.y, h2 = hf.z, h3 = hf.w;

    const int t0 = c * CL;
    const float* pdelta = xz + (size_t)b * TT * 8192 + (size_t)t0 * 8192 + d;
    const float* pz     = pdelta + 4096;
    const float* px     = xs + (size_t)b * TT * 4096 + (size_t)t0 * 4096 + d;
    const float* pB     = dbc + ((size_t)b * TT + t0) * 160 + 128 + sub * 4;
    const float* pC     = pB + 16;
    __bf16* py = ys16 + (size_t)b * TT * 4096 + (size_t)t0 * 4096 + d;

    for (int t = 0; t < CL; t++) {
        const float delta = pdelta[(size_t)t * 8192];
        const float xv    = px[(size_t)t * 4096];
        const float4 Bv   = *(const float4*)&pB[(size_t)t * 160];
        const float4 Cv   = *(const float4*)&pC[(size_t)t * 160];
        const float dx = delta * xv;

        h0 = __expf(delta * Ad0) * h0 + dx * Bv.x;
        h1 = __expf(delta * Ad1) * h1 + dx * Bv.y;
        h2 = __expf(delta * Ad2) * h2 + dx * Bv.z;
        h3 = __expf(delta * Ad3) * h3 + dx * Bv.w;

        float y = h0 * Cv.x + h1 * Cv.y + h2 * Cv.z + h3 * Cv.w;
        y += __shfl_xor(y, 1);
        y += __shfl_xor(y, 2);

        if (sub == 0) {
            const float zv = pz[(size_t)t * 8192];
            y += Dp * xv;
            const float g = zv / (1.f + __expf(-zv));
            py[(size_t)t * 4096] = (__bf16)(y * g);
        }
    }
}

// ---------------------------------------------------------------------------
extern "C" void kernel_launch(void* const* d_in, const int* in_sizes, int n_in,
                              void* d_out, int out_size, void* d_ws, size_t ws_size,
                              hipStream_t stream)
{
    const float* x          = (const float*)d_in[0];
    const float* h_in       = (const float*)d_in[1];
    const float* conv_cache = (const float*)d_in[2];
    const float* in_proj_w  = (const float*)d_in[3];
    const float* conv_w     = (const float*)d_in[4];
    const float* conv_b     = (const float*)d_in[5];
    const float* x_proj_w   = (const float*)d_in[6];
    const float* dt_proj_w  = (const float*)d_in[7];
    const float* dt_proj_b  = (const float*)d_in[8];
    const float* A_log      = (const float*)d_in[9];
    const float* D_param    = (const float*)d_in[10];
    const float* out_proj_w = (const float*)d_in[11];

    float* out    = (float*)d_out;
    float* h_out  = (float*)d_out + (size_t)NB * TT * D_MODEL;
    float* cc_out = h_out + (size_t)NB * D_INNER * D_STATE;

    // P/S scratch in the (dead until final GEMM) `out` region
    float* Pbuf = out;
    float* Sbuf = out + 2097152;

    char* ws = (char*)d_ws;
    // [0,64M)        xz fp32 (2048x8192)
    // [64M,72M)      x16 bf16  | [72M,104M) wi16 bf16   (dead after in_proj)
    // [64M,96M)      xs fp32   (conv output, aliases x16+wi16)
    // [96M,112M)     xs16 bf16 (conv output, aliases wi16 tail)
    // [112M,...)     dbc fp32, ys16, wx16(pad 256x4096), dt16, wdt16
    float*  xz    = (float*)(ws);
    __bf16* x16   = (__bf16*)(ws + 67108864);
    __bf16* wi16  = (__bf16*)(ws + 75497472);
    float*  xs    = (float*)(ws + 67108864);
    __bf16* xs16  = (__bf16*)(ws + 100663296);
    float*  dbc   = (float*)(ws + 117440512);    // 1310720 B
    __bf16* ys16  = (__bf16*)(ws + 118751232);   // 16777216 B
    __bf16* wx16  = (__bf16*)(ws + 135528448);   // 2097152 B (256x4096)
    __bf16* dt16  = (__bf16*)(ws + 137625600);   // 524288 B  (2048x128)
    __bf16* wdt16 = (__bf16*)(ws + 138149888);   // 1048576 B (4096x128)
    __bf16* wo16  = (__bf16*)(ws);               // aliases xz after scan

    dim3 blk(256);

    // 0) weight/input casts + zero-inits
    cast_f32_bf16<<<dim3((D_MODEL * M_TOT / 8 + 255) / 256), blk, 0, stream>>>(
        x, x16, D_MODEL * M_TOT / 8);
    cast_f32_bf16<<<dim3((8192 * 2048 / 8 + 255) / 256), blk, 0, stream>>>(
        in_proj_w, wi16, 8192 * 2048 / 8);
    hipMemsetAsync(wx16, 0, 2097152, stream);
    cast_f32_bf16<<<dim3((160 * 4096 / 8 + 255) / 256), blk, 0, stream>>>(
        x_proj_w, wx16, 160 * 4096 / 8);
    cast_f32_bf16<<<dim3((4096 * 128 / 8 + 255) / 256), blk, 0, stream>>>(
        dt_proj_w, wdt16, 4096 * 128 / 8);
    hipMemsetAsync(dbc, 0, (size_t)M_TOT * 160 * 4, stream);

    // 1) xz = x @ in_proj_w^T  (M=2048, N=8192, K=2048)
    gemm_bf16_nt<0><<<dim3(64, 16, 1), blk, 0, stream>>>(
        x16, 2048, wi16, 2048, xz, 8192, 2048, 8192, nullptr);

    // 2) conv + silu -> xs (fp32 + bf16), new_conv_cache
    conv_silu<<<dim3(TT / TC, D_INNER / 256, NB), blk, 0, stream>>>(
        xz, conv_cache, conv_w, conv_b, xs, xs16, cc_out);

    // 3) dbc = xs @ x_proj_w^T  (bf16 MFMA, split-K=8, atomic; N=160 guarded)
    gemm_bf16_nt<2><<<dim3(2, 16, 8), blk, 0, stream>>>(
        xs16, 4096, wx16, 4096, dbc, 160, 512, 160, nullptr);

    // 4) delta = softplus(dbc[:, :128] @ dt_proj_w^T + b) -> xi region of xz
    cast_dt16<<<dim3(128), blk, 0, stream>>>(dbc, dt16);
    gemm_bf16_nt<1><<<dim3(32, 16, 1), blk, 0, stream>>>(
        dt16, 128, wdt16, 128, xz, 8192, 128, 4096, dt_proj_b);

    // 5) chunked selective scan -> ys16 + h_out
    scan_phase_a<<<dim3(NB * D_INNER * NC * 4 / 256), blk, 0, stream>>>(
        xz, dbc, xs, A_log, Pbuf, Sbuf);
    scan_phase_b<<<dim3(NB * D_INNER * D_STATE / 256), blk, 0, stream>>>(
        Pbuf, Sbuf, h_in, h_out);
    scan_phase_c<<<dim3(NB * D_INNER * NC * 4 / 256), blk, 0, stream>>>(
        xz, dbc, xs, Pbuf, A_log, D_param, ys16);

    // 6) out = ys @ out_proj_w^T  (M=2048, N=2048, K=4096)
    cast_f32_bf16<<<dim3((2048 * 4096 / 8 + 255) / 256), blk, 0, stream>>>(
        out_proj_w, wo16, 2048 * 4096 / 8);
    gemm_bf16_nt<0><<<dim3(16, 16, 1), blk, 0, stream>>>(
        ys16, 4096, wo16, 4096, out, 2048, 4096, 2048, nullptr);
}

// Round 5
// 512.500 us; speedup vs baseline: 6.0950x; 1.0599x over previous
//
#include <hip/hip_runtime.h>
#include <hip/hip_bf16.h>
#include <math.h>

#define D_MODEL 2048
#define D_INNER 4096
#define D_STATE 16
#define D_CONV  4
#define DT_RANK 128
#define NB      2
#define TT      1024
#define M_TOT   (NB * TT)          // 2048 rows for all GEMMs
#define NC      16                 // scan chunks
#define CL      64                 // chunk length (TT/NC)
#define TC      16                 // conv t-chunk

typedef __bf16 bf16x8_t __attribute__((ext_vector_type(8)));
typedef float  f32x4_t  __attribute__((ext_vector_type(4)));

// ---------------------------------------------------------------------------
// Fused cast/zero kernel: one dispatch does all fp32->bf16 weight/input casts
// plus the zero-inits (wx16 pad rows, dbc accumulator).  Segments in units of
// 8 elements:
//   [0,524288)            x      -> x16
//   [524288,2621440)      wi     -> wi16
//   [2621440,3670016)     wo     -> wo16
//   [3670016,3751936)     wx     -> wx16 (data rows)
//   [3751936,3801088)     zeros  -> wx16 (pad rows)
//   [3801088,3866624)     wdt    -> wdt16
//   [3866624,3948544)     zeros  -> dbc (fp32 region, written as bf16 zeros)
// ---------------------------------------------------------------------------
__global__ __launch_bounds__(256) void fused_cast(
    const float* __restrict__ x,  const float* __restrict__ wi,
    const float* __restrict__ wo, const float* __restrict__ wx,
    const float* __restrict__ wdt,
    __bf16* __restrict__ x16,  __bf16* __restrict__ wi16,
    __bf16* __restrict__ wo16, __bf16* __restrict__ wx16,
    __bf16* __restrict__ wdt16, __bf16* __restrict__ dbc16)
{
    const size_t g = (size_t)blockIdx.x * 256 + threadIdx.x;
    const float* src; __bf16* dst; size_t off;
    if      (g < 524288)  { src = x;   dst = x16;   off = g; }
    else if (g < 2621440) { src = wi;  dst = wi16;  off = g - 524288; }
    else if (g < 3670016) { src = wo;  dst = wo16;  off = g - 2621440; }
    else if (g < 3801088) { off = g - 3670016; dst = wx16;
                            src = (g < 3751936) ? wx : nullptr; }
    else if (g < 3866624) { src = wdt; dst = wdt16; off = g - 3801088; }
    else                  { src = nullptr; dst = dbc16; off = g - 3866624; }

    bf16x8_t v;
    if (src) {
        const float4 f0 = ((const float4*)src)[2 * off];
        const float4 f1 = ((const float4*)src)[2 * off + 1];
        v[0] = (__bf16)f0.x; v[1] = (__bf16)f0.y; v[2] = (__bf16)f0.z; v[3] = (__bf16)f0.w;
        v[4] = (__bf16)f1.x; v[5] = (__bf16)f1.y; v[6] = (__bf16)f1.z; v[7] = (__bf16)f1.w;
    } else {
        v = (bf16x8_t)(__bf16)0.f;
    }
    ((bf16x8_t*)dst)[off] = v;
}

// dbc (2048x160) cols 0:128 -> dt16 (2048x128) bf16.  32768 threads.
__global__ __launch_bounds__(256) void cast_dt16(
    const float* __restrict__ dbc, __bf16* __restrict__ dt16)
{
    int i = blockIdx.x * 256 + threadIdx.x;   // 0..32767
    int row = i >> 4, chunk = i & 15;
    const float* s = dbc + (size_t)row * 160 + chunk * 8;
    const float4 f0 = *(const float4*)s;
    const float4 f1 = *(const float4*)(s + 4);
    bf16x8_t v;
    v[0] = (__bf16)f0.x; v[1] = (__bf16)f0.y; v[2] = (__bf16)f0.z; v[3] = (__bf16)f0.w;
    v[4] = (__bf16)f1.x; v[5] = (__bf16)f1.y; v[6] = (__bf16)f1.z; v[7] = (__bf16)f1.w;
    ((bf16x8_t*)(dt16 + (size_t)row * 128))[chunk] = v;
}

// ---------------------------------------------------------------------------
// bf16 MFMA GEMM: C(M,Nmax) OutT (+EPI) = A(M,K;lda) bf16 @ W(N,K;ldw)^T.
// 128x128 tile, BK=32, 256 threads (4 waves), m97 structure.
// Split-K via gridDim.z (koff = z*Kloop).  EPI: 0 store (OutT float/bf16),
// 1 +bias softplus (float), 2 atomicAdd (float).  Column guard n < Nmax.
// ---------------------------------------------------------------------------
template <int EPI, typename OutT>
__global__ __launch_bounds__(256) void gemm_bf16_nt(
    const __bf16* __restrict__ A, int lda,
    const __bf16* __restrict__ W, int ldw,
    OutT* __restrict__ C, int ldc,
    int Kloop, int Nmax, const float* __restrict__ bias)
{
    __shared__ __bf16 As[128 * 32];
    __shared__ __bf16 Bs[128 * 32];

    const int tid  = threadIdx.x;
    const int wave = tid >> 6;
    const int lane = tid & 63;
    const int m0 = blockIdx.y * 128;
    const int n0 = blockIdx.x * 128;
    const int mw = (wave >> 1) * 64;
    const int nw = (wave & 1) * 64;
    const int koff = blockIdx.z * Kloop;

    f32x4_t acc[4][4] = {};

    const int g0 = wave * 2;
    const int rA = g0 * 16 + (lane >> 2);
    const int kk = (lane & 3) * 8;

    const __bf16* gA0 = A + (size_t)(m0 + rA) * lda + kk + koff;
    const __bf16* gA1 = gA0 + (size_t)16 * lda;
    const __bf16* gB0 = W + (size_t)(n0 + rA) * ldw + kk + koff;
    const __bf16* gB1 = gB0 + (size_t)16 * ldw;

    __bf16* lA0 = &As[(size_t)g0 * 512];
    __bf16* lA1 = &As[(size_t)(g0 + 1) * 512];
    __bf16* lB0 = &Bs[(size_t)g0 * 512];
    __bf16* lB1 = &Bs[(size_t)(g0 + 1) * 512];

    const int fr = lane & 15;
    const int fk = (lane >> 4) * 8;

    for (int k0 = 0; k0 < Kloop; k0 += 32) {
        __builtin_amdgcn_global_load_lds(
            (const __attribute__((address_space(1))) void*)(gA0 + k0),
            (__attribute__((address_space(3))) void*)lA0, 16, 0, 0);
        __builtin_amdgcn_global_load_lds(
            (const __attribute__((address_space(1))) void*)(gA1 + k0),
            (__attribute__((address_space(3))) void*)lA1, 16, 0, 0);
        __builtin_amdgcn_global_load_lds(
            (const __attribute__((address_space(1))) void*)(gB0 + k0),
            (__attribute__((address_space(3))) void*)lB0, 16, 0, 0);
        __builtin_amdgcn_global_load_lds(
            (const __attribute__((address_space(1))) void*)(gB1 + k0),
            (__attribute__((address_space(3))) void*)lB1, 16, 0, 0);
        __syncthreads();

        bf16x8_t av[4], bv[4];
#pragma unroll
        for (int mt = 0; mt < 4; mt++)
            av[mt] = *(const bf16x8_t*)&As[(mw + mt * 16 + fr) * 32 + fk];
#pragma unroll
        for (int nt = 0; nt < 4; nt++)
            bv[nt] = *(const bf16x8_t*)&Bs[(nw + nt * 16 + fr) * 32 + fk];

#pragma unroll
        for (int mt = 0; mt < 4; mt++)
#pragma unroll
            for (int nt = 0; nt < 4; nt++)
                acc[mt][nt] = __builtin_amdgcn_mfma_f32_16x16x32_bf16(
                    av[mt], bv[nt], acc[mt][nt], 0, 0, 0);
        __syncthreads();
    }

    // C/D layout: col = lane&15, row = (lane>>4)*4 + reg
    const int cn = n0 + nw + (lane & 15);
    const int rb = m0 + mw + (lane >> 4) * 4;
#pragma unroll
    for (int mt = 0; mt < 4; mt++)
#pragma unroll
        for (int nt = 0; nt < 4; nt++) {
            const int n = cn + nt * 16;
            if (n >= Nmax) continue;
#pragma unroll
            for (int r = 0; r < 4; r++) {
                float v = acc[mt][nt][r];
                OutT* p = &C[(size_t)(rb + mt * 16 + r) * ldc + n];
                if (EPI == 1) {
                    v += bias[n];
                    v = (v > 20.f) ? v : log1pf(__expf(v));
                    *p = (OutT)v;
                } else if (EPI == 2) {
                    atomicAdd((float*)p, v);
                } else {
                    *p = (OutT)v;
                }
            }
        }
}

// ---------------------------------------------------------------------------
// Causal depthwise conv (width 4) + bias + silu, t-chunk TC per thread.
// Reads xi (bf16, cols 0:4096 of xz16, ld 8192); emits xs16 bf16 + cache.
// ---------------------------------------------------------------------------
__global__ __launch_bounds__(256) void conv_silu(
    const __bf16* __restrict__ xz16,
    const float* __restrict__ conv_cache,
    const float* __restrict__ conv_w,
    const float* __restrict__ conv_b,
    __bf16* __restrict__ xs16,
    float* __restrict__ cc_out)
{
    const int b  = blockIdx.z;
    const int d  = blockIdx.y * 256 + threadIdx.x;
    const int t0 = blockIdx.x * TC;

    const float4 w  = *(const float4*)&conv_w[d * 4];
    const float bias = conv_b[d];

    float v[TC + 3];
    if (t0 == 0) {
        v[0] = conv_cache[(b * D_INNER + d) * 3 + 0];
        v[1] = conv_cache[(b * D_INNER + d) * 3 + 1];
        v[2] = conv_cache[(b * D_INNER + d) * 3 + 2];
    } else {
        v[0] = (float)xz16[(size_t)(b * TT + t0 - 3) * 8192 + d];
        v[1] = (float)xz16[(size_t)(b * TT + t0 - 2) * 8192 + d];
        v[2] = (float)xz16[(size_t)(b * TT + t0 - 1) * 8192 + d];
    }
#pragma unroll
    for (int k = 0; k < TC; k++)
        v[k + 3] = (float)xz16[(size_t)(b * TT + t0 + k) * 8192 + d];

#pragma unroll
    for (int k = 0; k < TC; k++) {
        float c = v[k] * w.x + v[k + 1] * w.y + v[k + 2] * w.z + v[k + 3] * w.w + bias;
        float s = c / (1.f + __expf(-c));
        xs16[(size_t)(b * TT + t0 + k) * 4096 + d] = (__bf16)s;
    }

    if (t0 + TC == TT) {
        cc_out[(b * D_INNER + d) * 3 + 0] = v[TC];
        cc_out[(b * D_INNER + d) * 3 + 1] = v[TC + 1];
        cc_out[(b * D_INNER + d) * 3 + 2] = v[TC + 2];
    }
}

// ---------------------------------------------------------------------------
// Chunked selective scan (3 phases).  P/S layout: ((b*NC+c)*4096+d)*16+n.
// delta: fp32 (2048,4096).  xs: bf16.  z: bf16 (cols 4096:8192 of xz16).
// ---------------------------------------------------------------------------
__global__ __launch_bounds__(256) void scan_phase_a(
    const float* __restrict__ delta_p,   // (2048,4096) fp32
    const float* __restrict__ dbc,       // (2048,160): B at 128
    const __bf16* __restrict__ xs16,
    const float* __restrict__ A_log,
    float* __restrict__ P,
    float* __restrict__ S)
{
    const int idx = blockIdx.x * 256 + threadIdx.x;
    const int sub = idx & 3;
    const int d   = (idx >> 2) & 4095;
    const int c   = (idx >> 14) & (NC - 1);
    const int b   = idx >> 18;

    const float4 Af = *(const float4*)&A_log[d * 16 + sub * 4];
    const float Ad0 = -__expf(Af.x), Ad1 = -__expf(Af.y);
    const float Ad2 = -__expf(Af.z), Ad3 = -__expf(Af.w);

    const int t0 = c * CL;
    const float*  pdelta = delta_p + (size_t)(b * TT + t0) * 4096 + d;
    const __bf16* px     = xs16 + (size_t)(b * TT + t0) * 4096 + d;
    const float*  pB     = dbc + ((size_t)b * TT + t0) * 160 + 128 + sub * 4;

    float h0 = 0.f, h1 = 0.f, h2 = 0.f, h3 = 0.f, sd = 0.f;
    for (int t = 0; t < CL; t++) {
        const float delta = pdelta[(size_t)t * 4096];
        const float xv    = (float)px[(size_t)t * 4096];
        const float4 Bv   = *(const float4*)&pB[(size_t)t * 160];
        const float dx = delta * xv;
        h0 = __expf(delta * Ad0) * h0 + dx * Bv.x;
        h1 = __expf(delta * Ad1) * h1 + dx * Bv.y;
        h2 = __expf(delta * Ad2) * h2 + dx * Bv.z;
        h3 = __expf(delta * Ad3) * h3 + dx * Bv.w;
        sd += delta;
    }
    const size_t o = ((size_t)(b * NC + c) * 4096 + d) * 16 + sub * 4;
    *(float4*)&P[o] = make_float4(__expf(Ad0 * sd), __expf(Ad1 * sd),
                                  __expf(Ad2 * sd), __expf(Ad3 * sd));
    *(float4*)&S[o] = make_float4(h0, h1, h2, h3);
}

__global__ __launch_bounds__(256) void scan_phase_b(
    float* __restrict__ P,            // in: decay; out: h_start
    const float* __restrict__ S,
    const float* __restrict__ h_in,
    float* __restrict__ h_out)
{
    const int idx = blockIdx.x * 256 + threadIdx.x;   // 131072
    const int n = idx & 15;
    const int d = (idx >> 4) & 4095;
    const int b = idx >> 16;

    float h = h_in[((size_t)b * 4096 + d) * 16 + n];
#pragma unroll
    for (int c = 0; c < NC; c++) {
        const size_t o = ((size_t)(b * NC + c) * 4096 + d) * 16 + n;
        const float p = P[o], s = S[o];
        P[o] = h;
        h = p * h + s;
    }
    h_out[((size_t)b * 4096 + d) * 16 + n] = h;
}

__global__ __launch_bounds__(256) void scan_phase_c(
    const float* __restrict__ delta_p,
    const __bf16* __restrict__ xz16,     // z at cols 4096:8192
    const float* __restrict__ dbc,       // B at 128, C at 144
    const __bf16* __restrict__ xs16,
    const float* __restrict__ Hs,        // h_start (the rewritten P)
    const float* __restrict__ A_log,
    const float* __restrict__ D_param,
    __bf16* __restrict__ ys16)
{
    const int idx = blockIdx.x * 256 + threadIdx.x;
    const int sub = idx & 3;
    const int d   = (idx >> 2) & 4095;
    const int c   = (idx >> 14) & (NC - 1);
    const int b   = idx >> 18;

    const float4 Af = *(const float4*)&A_log[d * 16 + sub * 4];
    const float Ad0 = -__expf(Af.x), Ad1 = -__expf(Af.y);
    const float Ad2 = -__expf(Af.z), Ad3 = -__expf(Af.w);
    const float Dp = D_param[d];

    const size_t o = ((size_t)(b * NC + c) * 4096 + d) * 16 + sub * 4;
    float4 hf = *(const float4*)&Hs[o];
    float h0 = hf.x, h1 = hf.y, h2 = hf.z, h3 = hf.w;

    const int t0 = c * CL;
    const float*  pdelta = delta_p + (size_t)(b * TT + t0) * 4096 + d;
    const __bf16* pz     = xz16 + (size_t)(b * TT + t0) * 8192 + 4096 + d;
    const __bf16* px     = xs16 + (size_t)(b * TT + t0) * 4096 + d;
    const float*  pB     = dbc + ((size_t)b * TT + t0) * 160 + 128 + sub * 4;
    const float*  pC     = pB + 16;
    __bf16* py = ys16 + (size_t)(b * TT + t0) * 4096 + d;

    for (int t = 0; t < CL; t++) {
        const float delta = pdelta[(size_t)t * 4096];
        const float xv    = (float)px[(size_t)t * 4096];
        const float4 Bv   = *(const float4*)&pB[(size_t)t * 160];
        const float4 Cv   = *(const float4*)&pC[(size_t)t * 160];
        const float dx = delta * xv;

        h0 = __expf(delta * Ad0) * h0 + dx * Bv.x;
        h1 = __expf(delta * Ad1) * h1 + dx * Bv.y;
        h2 = __expf(delta * Ad2) * h2 + dx * Bv.z;
        h3 = __expf(delta * Ad3) * h3 + dx * Bv.w;

        float y = h0 * Cv.x + h1 * Cv.y + h2 * Cv.z + h3 * Cv.w;
        y += __shfl_xor(y, 1);
        y += __shfl_xor(y, 2);

        if (sub == 0) {
            const float zv = (float)pz[(size_t)t * 8192];
            y += Dp * xv;
            const float g = zv / (1.f + __expf(-zv));
            py[(size_t)t * 4096] = (__bf16)(y * g);
        }
    }
}

// ---------------------------------------------------------------------------
extern "C" void kernel_launch(void* const* d_in, const int* in_sizes, int n_in,
                              void* d_out, int out_size, void* d_ws, size_t ws_size,
                              hipStream_t stream)
{
    const float* x          = (const float*)d_in[0];
    const float* h_in       = (const float*)d_in[1];
    const float* conv_cache = (const float*)d_in[2];
    const float* in_proj_w  = (const float*)d_in[3];
    const float* conv_w     = (const float*)d_in[4];
    const float* conv_b     = (const float*)d_in[5];
    const float* x_proj_w   = (const float*)d_in[6];
    const float* dt_proj_w  = (const float*)d_in[7];
    const float* dt_proj_b  = (const float*)d_in[8];
    const float* A_log      = (const float*)d_in[9];
    const float* D_param    = (const float*)d_in[10];
    const float* out_proj_w = (const float*)d_in[11];

    float* out    = (float*)d_out;
    float* h_out  = (float*)d_out + (size_t)NB * TT * D_MODEL;
    float* cc_out = h_out + (size_t)NB * D_INNER * D_STATE;

    // P/S scratch in the (dead until final GEMM) `out` region
    float* Pbuf = out;
    float* Sbuf = out + 2097152;

    char* ws = (char*)d_ws;
    // [0, 33.5M)       xz16 bf16 (2048x8192): xi | z
    // [33.5M, 41.9M)   x16 bf16 (2048x2048)        -- dead after in_proj
    // [41.9M, 75.5M)   wi16 bf16 (8192x2048)       -- dead after in_proj
    // [41.9M, 75.5M)   delta fp32 (2048x4096), written by dt_proj (alias)
    // [75.5M, 92.3M)   wo16 bf16 (2048x4096)
    // [92.3M, 109M)    xs16 bf16 (2048x4096)
    // [109M, 110.4M)   dbc fp32 (2048x160)
    // [110.4M, 127.1M) ys16 bf16 (2048x4096)
    // [127.1M, 129.2M) wx16 bf16 (256x4096, padded)
    // [129.2M, 129.8M) dt16 bf16 (2048x128)
    // [129.8M, 130.8M) wdt16 bf16 (4096x128)
    __bf16* xz16  = (__bf16*)(ws);
    __bf16* x16   = (__bf16*)(ws + 33554432);
    __bf16* wi16  = (__bf16*)(ws + 41943040);
    float*  delta = (float*)(ws + 41943040);     // aliases wi16 (after in_proj)
    __bf16* wo16  = (__bf16*)(ws + 75497472);
    __bf16* xs16  = (__bf16*)(ws + 92274688);
    float*  dbc   = (float*)(ws + 109051904);
    __bf16* ys16  = (__bf16*)(ws + 110362624);
    __bf16* wx16  = (__bf16*)(ws + 127139840);
    __bf16* dt16  = (__bf16*)(ws + 129236992);
    __bf16* wdt16 = (__bf16*)(ws + 129761280);

    dim3 blk(256);

    // 0) all casts + zero-inits in ONE dispatch (3948544 groups / 256)
    fused_cast<<<dim3(15424), blk, 0, stream>>>(
        x, in_proj_w, out_proj_w, x_proj_w, dt_proj_w,
        x16, wi16, wo16, wx16, wdt16, (__bf16*)dbc);

    // 1) xz16 = x @ in_proj_w^T  (M=2048, N=8192, K=2048; bf16 out)
    gemm_bf16_nt<0, __bf16><<<dim3(64, 16, 1), blk, 0, stream>>>(
        x16, 2048, wi16, 2048, xz16, 8192, 2048, 8192, nullptr);

    // 2) conv + silu -> xs16, new_conv_cache
    conv_silu<<<dim3(TT / TC, D_INNER / 256, NB), blk, 0, stream>>>(
        xz16, conv_cache, conv_w, conv_b, xs16, cc_out);

    // 3) dbc = xs @ x_proj_w^T  (split-K=8, atomic; N=160 guarded)
    gemm_bf16_nt<2, float><<<dim3(2, 16, 8), blk, 0, stream>>>(
        xs16, 4096, wx16, 4096, dbc, 160, 512, 160, nullptr);

    // 4) delta = softplus(dbc[:, :128] @ dt_proj_w^T + b)  (fp32 out)
    cast_dt16<<<dim3(128), blk, 0, stream>>>(dbc, dt16);
    gemm_bf16_nt<1, float><<<dim3(32, 16, 1), blk, 0, stream>>>(
        dt16, 128, wdt16, 128, delta, 4096, 128, 4096, dt_proj_b);

    // 5) chunked selective scan -> ys16 + h_out
    scan_phase_a<<<dim3(NB * D_INNER * NC * 4 / 256), blk, 0, stream>>>(
        delta, dbc, xs16, A_log, Pbuf, Sbuf);
    scan_phase_b<<<dim3(NB * D_INNER * D_STATE / 256), blk, 0, stream>>>(
        Pbuf, Sbuf, h_in, h_out);
    scan_phase_c<<<dim3(NB * D_INNER * NC * 4 / 256), blk, 0, stream>>>(
        delta, xz16, dbc, xs16, Pbuf, A_log, D_param, ys16);

    // 6) out = ys @ out_proj_w^T  (split-K=2, atomic into zeroed out)
    hipMemsetAsync(out, 0, (size_t)M_TOT * D_MODEL * 4, stream);
    gemm_bf16_nt<2, float><<<dim3(16, 16, 2), blk, 0, stream>>>(
        ys16, 4096, wo16, 4096, out, 2048, 2048, 2048, nullptr);
}

// Round 6
// 504.799 us; speedup vs baseline: 6.1880x; 1.0153x over previous
//
#include <hip/hip_runtime.h>
#include <hip/hip_bf16.h>
#include <math.h>

#define D_MODEL 2048
#define D_INNER 4096
#define D_STATE 16
#define D_CONV  4
#define DT_RANK 128
#define NB      2
#define TT      1024
#define M_TOT   (NB * TT)          // 2048 rows for all GEMMs
#define NC      16                 // scan chunks
#define CL      64                 // chunk length (TT/NC)
#define TC      16                 // conv t-chunk

typedef __bf16 bf16x8_t __attribute__((ext_vector_type(8)));
typedef float  f32x4_t  __attribute__((ext_vector_type(4)));

// ---------------------------------------------------------------------------
// Fused cast/zero kernel: one dispatch does all fp32->bf16 weight/input casts
// plus the zero-inits (wx16 pad rows, dbc accumulator).  Segments in units of
// 8 elements.
// ---------------------------------------------------------------------------
__global__ __launch_bounds__(256) void fused_cast(
    const float* __restrict__ x,  const float* __restrict__ wi,
    const float* __restrict__ wo, const float* __restrict__ wx,
    const float* __restrict__ wdt,
    __bf16* __restrict__ x16,  __bf16* __restrict__ wi16,
    __bf16* __restrict__ wo16, __bf16* __restrict__ wx16,
    __bf16* __restrict__ wdt16, __bf16* __restrict__ dbc16)
{
    const size_t g = (size_t)blockIdx.x * 256 + threadIdx.x;
    const float* src; __bf16* dst; size_t off;
    if      (g < 524288)  { src = x;   dst = x16;   off = g; }
    else if (g < 2621440) { src = wi;  dst = wi16;  off = g - 524288; }
    else if (g < 3670016) { src = wo;  dst = wo16;  off = g - 2621440; }
    else if (g < 3801088) { off = g - 3670016; dst = wx16;
                            src = (g < 3751936) ? wx : nullptr; }
    else if (g < 3866624) { src = wdt; dst = wdt16; off = g - 3801088; }
    else                  { src = nullptr; dst = dbc16; off = g - 3866624; }

    bf16x8_t v;
    if (src) {
        const float4 f0 = ((const float4*)src)[2 * off];
        const float4 f1 = ((const float4*)src)[2 * off + 1];
        v[0] = (__bf16)f0.x; v[1] = (__bf16)f0.y; v[2] = (__bf16)f0.z; v[3] = (__bf16)f0.w;
        v[4] = (__bf16)f1.x; v[5] = (__bf16)f1.y; v[6] = (__bf16)f1.z; v[7] = (__bf16)f1.w;
    } else {
        v = (bf16x8_t)(__bf16)0.f;
    }
    ((bf16x8_t*)dst)[off] = v;
}

// ---------------------------------------------------------------------------
// bf16 MFMA GEMM: C(M,Nmax) OutT (+EPI) = A(M,K;lda) bf16 @ W(N,K;ldw)^T.
// 128x128 tile, 256 threads (4 waves).  KSTEP = 32 or 64: k-chunk per
// barrier pair (KSTEP=64 stages two 128x32 panels -> half the barriers).
// Split-K via gridDim.z.  EPI: 0 store, 1 +bias softplus, 2 atomicAdd.
// ---------------------------------------------------------------------------
template <int EPI, int KSTEP, typename OutT>
__global__ __launch_bounds__(256) void gemm_bf16_nt(
    const __bf16* __restrict__ A, int lda,
    const __bf16* __restrict__ W, int ldw,
    OutT* __restrict__ C, int ldc,
    int Kloop, int Nmax, const float* __restrict__ bias)
{
    __shared__ __bf16 As[128 * KSTEP];
    __shared__ __bf16 Bs[128 * KSTEP];

    const int tid  = threadIdx.x;
    const int wave = tid >> 6;
    const int lane = tid & 63;
    const int m0 = blockIdx.y * 128;
    const int n0 = blockIdx.x * 128;
    const int mw = (wave >> 1) * 64;
    const int nw = (wave & 1) * 64;
    const int koff = blockIdx.z * Kloop;

    f32x4_t acc[4][4] = {};

    const int g0 = wave * 2;
    const int rA = g0 * 16 + (lane >> 2);
    const int kk = (lane & 3) * 8;

    const __bf16* gA0 = A + (size_t)(m0 + rA) * lda + kk + koff;
    const __bf16* gA1 = gA0 + (size_t)16 * lda;
    const __bf16* gB0 = W + (size_t)(n0 + rA) * ldw + kk + koff;
    const __bf16* gB1 = gB0 + (size_t)16 * ldw;

    __bf16* lA0 = &As[(size_t)g0 * 512];
    __bf16* lA1 = &As[(size_t)(g0 + 1) * 512];
    __bf16* lB0 = &Bs[(size_t)g0 * 512];
    __bf16* lB1 = &Bs[(size_t)(g0 + 1) * 512];

    const int fr = lane & 15;
    const int fk = (lane >> 4) * 8;

    for (int k0 = 0; k0 < Kloop; k0 += KSTEP) {
#pragma unroll
        for (int p = 0; p < KSTEP / 32; p++) {
            const int kp = k0 + p * 32;
            const int lp = p * 4096;   // panel offset (elements)
            __builtin_amdgcn_global_load_lds(
                (const __attribute__((address_space(1))) void*)(gA0 + kp),
                (__attribute__((address_space(3))) void*)(lA0 + lp), 16, 0, 0);
            __builtin_amdgcn_global_load_lds(
                (const __attribute__((address_space(1))) void*)(gA1 + kp),
                (__attribute__((address_space(3))) void*)(lA1 + lp), 16, 0, 0);
            __builtin_amdgcn_global_load_lds(
                (const __attribute__((address_space(1))) void*)(gB0 + kp),
                (__attribute__((address_space(3))) void*)(lB0 + lp), 16, 0, 0);
            __builtin_amdgcn_global_load_lds(
                (const __attribute__((address_space(1))) void*)(gB1 + kp),
                (__attribute__((address_space(3))) void*)(lB1 + lp), 16, 0, 0);
        }
        __syncthreads();

#pragma unroll
        for (int p = 0; p < KSTEP / 32; p++) {
            const int lp = p * 4096;
            bf16x8_t av[4], bv[4];
#pragma unroll
            for (int mt = 0; mt < 4; mt++)
                av[mt] = *(const bf16x8_t*)&As[lp + (mw + mt * 16 + fr) * 32 + fk];
#pragma unroll
            for (int nt = 0; nt < 4; nt++)
                bv[nt] = *(const bf16x8_t*)&Bs[lp + (nw + nt * 16 + fr) * 32 + fk];

#pragma unroll
            for (int mt = 0; mt < 4; mt++)
#pragma unroll
                for (int nt = 0; nt < 4; nt++)
                    acc[mt][nt] = __builtin_amdgcn_mfma_f32_16x16x32_bf16(
                        av[mt], bv[nt], acc[mt][nt], 0, 0, 0);
        }
        __syncthreads();
    }

    // C/D layout: col = lane&15, row = (lane>>4)*4 + reg
    const int cn = n0 + nw + (lane & 15);
    const int rb = m0 + mw + (lane >> 4) * 4;
#pragma unroll
    for (int mt = 0; mt < 4; mt++)
#pragma unroll
        for (int nt = 0; nt < 4; nt++) {
            const int n = cn + nt * 16;
            if (n >= Nmax) continue;
#pragma unroll
            for (int r = 0; r < 4; r++) {
                float v = acc[mt][nt][r];
                OutT* p = &C[(size_t)(rb + mt * 16 + r) * ldc + n];
                if (EPI == 1) {
                    v += bias[n];
                    v = (v > 20.f) ? v : log1pf(__expf(v));
                    *p = (OutT)v;
                } else if (EPI == 2) {
                    atomicAdd((float*)p, v);
                } else {
                    *p = (OutT)v;
                }
            }
        }
}

// ---------------------------------------------------------------------------
// dt_proj GEMM with inlined fp32->bf16 A staging (removes cast_dt16 pass).
// delta(2048,4096) = softplus(dbc[:, 0:128] @ wdt16(4096,128)^T + bias).
// A = dbc fp32 (ld 160).  K=128 fixed, BK=32.  grid (32,16), 256 thr.
// ---------------------------------------------------------------------------
__global__ __launch_bounds__(256) void gemm_dt(
    const float* __restrict__ A,      // dbc
    const __bf16* __restrict__ W,     // wdt16
    float* __restrict__ C,            // delta
    const float* __restrict__ bias)
{
    __shared__ __bf16 As[128 * 32];
    __shared__ __bf16 Bs[128 * 32];

    const int tid  = threadIdx.x;
    const int wave = tid >> 6;
    const int lane = tid & 63;
    const int m0 = blockIdx.y * 128;
    const int n0 = blockIdx.x * 128;
    const int mw = (wave >> 1) * 64;
    const int nw = (wave & 1) * 64;

    f32x4_t acc[4][4] = {};

    const int g0 = wave * 2;
    const int rA = g0 * 16 + (lane >> 2);
    const int kk = (lane & 3) * 8;

    const float*  gA0 = A + (size_t)(m0 + rA) * 160 + kk;
    const float*  gA1 = gA0 + (size_t)16 * 160;
    const __bf16* gB0 = W + (size_t)(n0 + rA) * 128 + kk;
    const __bf16* gB1 = gB0 + (size_t)16 * 128;

    __bf16* lA0 = &As[(size_t)g0 * 512];
    __bf16* lA1 = &As[(size_t)(g0 + 1) * 512];
    __bf16* lB0 = &Bs[(size_t)g0 * 512];
    __bf16* lB1 = &Bs[(size_t)(g0 + 1) * 512];

    const int fr = lane & 15;
    const int fk = (lane >> 4) * 8;

    for (int k0 = 0; k0 < 128; k0 += 32) {
        // A: load fp32, cast, ds_write (same LDS layout as global_load_lds)
        const float4 a0 = *(const float4*)(gA0 + k0);
        const float4 a1 = *(const float4*)(gA0 + k0 + 4);
        const float4 a2 = *(const float4*)(gA1 + k0);
        const float4 a3 = *(const float4*)(gA1 + k0 + 4);
        bf16x8_t va, vb;
        va[0] = (__bf16)a0.x; va[1] = (__bf16)a0.y; va[2] = (__bf16)a0.z; va[3] = (__bf16)a0.w;
        va[4] = (__bf16)a1.x; va[5] = (__bf16)a1.y; va[6] = (__bf16)a1.z; va[7] = (__bf16)a1.w;
        vb[0] = (__bf16)a2.x; vb[1] = (__bf16)a2.y; vb[2] = (__bf16)a2.z; vb[3] = (__bf16)a2.w;
        vb[4] = (__bf16)a3.x; vb[5] = (__bf16)a3.y; vb[6] = (__bf16)a3.z; vb[7] = (__bf16)a3.w;
        ((bf16x8_t*)lA0)[lane] = va;
        ((bf16x8_t*)lA1)[lane] = vb;
        __builtin_amdgcn_global_load_lds(
            (const __attribute__((address_space(1))) void*)(gB0 + k0),
            (__attribute__((address_space(3))) void*)lB0, 16, 0, 0);
        __builtin_amdgcn_global_load_lds(
            (const __attribute__((address_space(1))) void*)(gB1 + k0),
            (__attribute__((address_space(3))) void*)lB1, 16, 0, 0);
        __syncthreads();

        bf16x8_t av[4], bv[4];
#pragma unroll
        for (int mt = 0; mt < 4; mt++)
            av[mt] = *(const bf16x8_t*)&As[(mw + mt * 16 + fr) * 32 + fk];
#pragma unroll
        for (int nt = 0; nt < 4; nt++)
            bv[nt] = *(const bf16x8_t*)&Bs[(nw + nt * 16 + fr) * 32 + fk];

#pragma unroll
        for (int mt = 0; mt < 4; mt++)
#pragma unroll
            for (int nt = 0; nt < 4; nt++)
                acc[mt][nt] = __builtin_amdgcn_mfma_f32_16x16x32_bf16(
                    av[mt], bv[nt], acc[mt][nt], 0, 0, 0);
        __syncthreads();
    }

    const int cn = n0 + nw + (lane & 15);
    const int rb = m0 + mw + (lane >> 4) * 4;
#pragma unroll
    for (int mt = 0; mt < 4; mt++)
#pragma unroll
        for (int nt = 0; nt < 4; nt++) {
            const int n = cn + nt * 16;
            const float bs = bias[n];
#pragma unroll
            for (int r = 0; r < 4; r++) {
                float v = acc[mt][nt][r] + bs;
                v = (v > 20.f) ? v : log1pf(__expf(v));
                C[(size_t)(rb + mt * 16 + r) * 4096 + n] = v;
            }
        }
}

// ---------------------------------------------------------------------------
// Causal depthwise conv (width 4) + bias + silu, t-chunk TC per thread.
// ---------------------------------------------------------------------------
__global__ __launch_bounds__(256) void conv_silu(
    const __bf16* __restrict__ xz16,
    const float* __restrict__ conv_cache,
    const float* __restrict__ conv_w,
    const float* __restrict__ conv_b,
    __bf16* __restrict__ xs16,
    float* __restrict__ cc_out)
{
    const int b  = blockIdx.z;
    const int d  = blockIdx.y * 256 + threadIdx.x;
    const int t0 = blockIdx.x * TC;

    const float4 w  = *(const float4*)&conv_w[d * 4];
    const float bias = conv_b[d];

    float v[TC + 3];
    if (t0 == 0) {
        v[0] = conv_cache[(b * D_INNER + d) * 3 + 0];
        v[1] = conv_cache[(b * D_INNER + d) * 3 + 1];
        v[2] = conv_cache[(b * D_INNER + d) * 3 + 2];
    } else {
        v[0] = (float)xz16[(size_t)(b * TT + t0 - 3) * 8192 + d];
        v[1] = (float)xz16[(size_t)(b * TT + t0 - 2) * 8192 + d];
        v[2] = (float)xz16[(size_t)(b * TT + t0 - 1) * 8192 + d];
    }
#pragma unroll
    for (int k = 0; k < TC; k++)
        v[k + 3] = (float)xz16[(size_t)(b * TT + t0 + k) * 8192 + d];

#pragma unroll
    for (int k = 0; k < TC; k++) {
        float c = v[k] * w.x + v[k + 1] * w.y + v[k + 2] * w.z + v[k + 3] * w.w + bias;
        float s = c / (1.f + __expf(-c));
        xs16[(size_t)(b * TT + t0 + k) * 4096 + d] = (__bf16)s;
    }

    if (t0 + TC == TT) {
        cc_out[(b * D_INNER + d) * 3 + 0] = v[TC];
        cc_out[(b * D_INNER + d) * 3 + 1] = v[TC + 1];
        cc_out[(b * D_INNER + d) * 3 + 2] = v[TC + 2];
    }
}

// ---------------------------------------------------------------------------
// Chunked selective scan (2 phases).  P/S layout: ((b*NC+c)*4096+d)*16+n.
// Phase A: per-chunk local scan from 0 -> S; chunk decay -> P.
// Phase C: combine P/S for chunks < c with h_in -> h_start (wave-uniform
// 16-iter fma chain), then re-run chunk scan emitting gated y; chunk NC-1
// threads write h_out.
// ---------------------------------------------------------------------------
__global__ __launch_bounds__(256) void scan_phase_a(
    const float* __restrict__ delta_p,   // (2048,4096) fp32
    const float* __restrict__ dbc,       // (2048,160): B at 128
    const __bf16* __restrict__ xs16,
    const float* __restrict__ A_log,
    float* __restrict__ P,
    float* __restrict__ S)
{
    const int idx = blockIdx.x * 256 + threadIdx.x;
    const int sub = idx & 3;
    const int d   = (idx >> 2) & 4095;
    const int c   = (idx >> 14) & (NC - 1);
    const int b   = idx >> 18;

    const float4 Af = *(const float4*)&A_log[d * 16 + sub * 4];
    const float Ad0 = -__expf(Af.x), Ad1 = -__expf(Af.y);
    const float Ad2 = -__expf(Af.z), Ad3 = -__expf(Af.w);

    const int t0 = c * CL;
    const float*  pdelta = delta_p + (size_t)(b * TT + t0) * 4096 + d;
    const __bf16* px     = xs16 + (size_t)(b * TT + t0) * 4096 + d;
    const float*  pB     = dbc + ((size_t)b * TT + t0) * 160 + 128 + sub * 4;

    float h0 = 0.f, h1 = 0.f, h2 = 0.f, h3 = 0.f, sd = 0.f;
    for (int t = 0; t < CL; t++) {
        const float delta = pdelta[(size_t)t * 4096];
        const float xv    = (float)px[(size_t)t * 4096];
        const float4 Bv   = *(const float4*)&pB[(size_t)t * 160];
        const float dx = delta * xv;
        h0 = __expf(delta * Ad0) * h0 + dx * Bv.x;
        h1 = __expf(delta * Ad1) * h1 + dx * Bv.y;
        h2 = __expf(delta * Ad2) * h2 + dx * Bv.z;
        h3 = __expf(delta * Ad3) * h3 + dx * Bv.w;
        sd += delta;
    }
    const size_t o = ((size_t)(b * NC + c) * 4096 + d) * 16 + sub * 4;
    *(float4*)&P[o] = make_float4(__expf(Ad0 * sd), __expf(Ad1 * sd),
                                  __expf(Ad2 * sd), __expf(Ad3 * sd));
    *(float4*)&S[o] = make_float4(h0, h1, h2, h3);
}

__global__ __launch_bounds__(256) void scan_phase_c(
    const float* __restrict__ delta_p,
    const __bf16* __restrict__ xz16,     // z at cols 4096:8192
    const float* __restrict__ dbc,       // B at 128, C at 144
    const __bf16* __restrict__ xs16,
    const float* __restrict__ P,         // chunk decay
    const float* __restrict__ S,         // chunk local scan
    const float* __restrict__ h_in,
    const float* __restrict__ A_log,
    const float* __restrict__ D_param,
    __bf16* __restrict__ ys16,
    float* __restrict__ h_out)
{
    const int idx = blockIdx.x * 256 + threadIdx.x;
    const int sub = idx & 3;
    const int d   = (idx >> 2) & 4095;
    const int c   = (idx >> 14) & (NC - 1);   // block-uniform
    const int b   = idx >> 18;

    const float4 Af = *(const float4*)&A_log[d * 16 + sub * 4];
    const float Ad0 = -__expf(Af.x), Ad1 = -__expf(Af.y);
    const float Ad2 = -__expf(Af.z), Ad3 = -__expf(Af.w);
    const float Dp = D_param[d];

    // h_start = combine(h_in, chunks 0..c-1)  — same arithmetic as old phase B
    float4 hf = *(const float4*)&h_in[((size_t)b * 4096 + d) * 16 + sub * 4];
    float h0 = hf.x, h1 = hf.y, h2 = hf.z, h3 = hf.w;
    for (int cc = 0; cc < c; cc++) {
        const size_t o2 = ((size_t)(b * NC + cc) * 4096 + d) * 16 + sub * 4;
        const float4 p = *(const float4*)&P[o2];
        const float4 s = *(const float4*)&S[o2];
        h0 = p.x * h0 + s.x;
        h1 = p.y * h1 + s.y;
        h2 = p.z * h2 + s.z;
        h3 = p.w * h3 + s.w;
    }

    const int t0 = c * CL;
    const float*  pdelta = delta_p + (size_t)(b * TT + t0) * 4096 + d;
    const __bf16* pz     = xz16 + (size_t)(b * TT + t0) * 8192 + 4096 + d;
    const __bf16* px     = xs16 + (size_t)(b * TT + t0) * 4096 + d;
    const float*  pB     = dbc + ((size_t)b * TT + t0) * 160 + 128 + sub * 4;
    const float*  pC     = pB + 16;
    __bf16* py = ys16 + (size_t)(b * TT + t0) * 4096 + d;

    for (int t = 0; t < CL; t++) {
        const float delta = pdelta[(size_t)t * 4096];
        const float xv    = (float)px[(size_t)t * 4096];
        const float4 Bv   = *(const float4*)&pB[(size_t)t * 160];
        const float4 Cv   = *(const float4*)&pC[(size_t)t * 160];
        const float dx = delta * xv;

        h0 = __expf(delta * Ad0) * h0 + dx * Bv.x;
        h1 = __expf(delta * Ad1) * h1 + dx * Bv.y;
        h2 = __expf(delta * Ad2) * h2 + dx * Bv.z;
        h3 = __expf(delta * Ad3) * h3 + dx * Bv.w;

        float y = h0 * Cv.x + h1 * Cv.y + h2 * Cv.z + h3 * Cv.w;
        y += __shfl_xor(y, 1);
        y += __shfl_xor(y, 2);

        if (sub == 0) {
            const float zv = (float)pz[(size_t)t * 8192];
            y += Dp * xv;
            const float g = zv / (1.f + __expf(-zv));
            py[(size_t)t * 4096] = (__bf16)(y * g);
        }
    }

    if (c == NC - 1) {
        *(float4*)&h_out[((size_t)b * 4096 + d) * 16 + sub * 4] =
            make_float4(h0, h1, h2, h3);
    }
}

// ---------------------------------------------------------------------------
extern "C" void kernel_launch(void* const* d_in, const int* in_sizes, int n_in,
                              void* d_out, int out_size, void* d_ws, size_t ws_size,
                              hipStream_t stream)
{
    const float* x          = (const float*)d_in[0];
    const float* h_in       = (const float*)d_in[1];
    const float* conv_cache = (const float*)d_in[2];
    const float* in_proj_w  = (const float*)d_in[3];
    const float* conv_w     = (const float*)d_in[4];
    const float* conv_b     = (const float*)d_in[5];
    const float* x_proj_w   = (const float*)d_in[6];
    const float* dt_proj_w  = (const float*)d_in[7];
    const float* dt_proj_b  = (const float*)d_in[8];
    const float* A_log      = (const float*)d_in[9];
    const float* D_param    = (const float*)d_in[10];
    const float* out_proj_w = (const float*)d_in[11];

    float* out    = (float*)d_out;
    float* h_out  = (float*)d_out + (size_t)NB * TT * D_MODEL;
    float* cc_out = h_out + (size_t)NB * D_INNER * D_STATE;

    // P/S scratch in the (dead until final GEMM) `out` region
    float* Pbuf = out;
    float* Sbuf = out + 2097152;

    char* ws = (char*)d_ws;
    // [0, 33.5M)       xz16 bf16 (2048x8192): xi | z
    // [33.5M, 41.9M)   x16 bf16 (2048x2048)        -- dead after in_proj
    // [41.9M, 75.5M)   wi16 bf16 (8192x2048)       -- dead after in_proj
    // [41.9M, 75.5M)   delta fp32 (2048x4096), written by dt_proj (alias)
    // [75.5M, 92.3M)   wo16 bf16 (2048x4096)
    // [92.3M, 109M)    xs16 bf16 (2048x4096)
    // [109M, 110.4M)   dbc fp32 (2048x160)
    // [110.4M, 127.1M) ys16 bf16 (2048x4096)
    // [127.1M, 129.2M) wx16 bf16 (256x4096, padded)
    // [129.2M, 130.3M) wdt16 bf16 (4096x128)
    __bf16* xz16  = (__bf16*)(ws);
    __bf16* x16   = (__bf16*)(ws + 33554432);
    __bf16* wi16  = (__bf16*)(ws + 41943040);
    float*  delta = (float*)(ws + 41943040);     // aliases wi16 (after in_proj)
    __bf16* wo16  = (__bf16*)(ws + 75497472);
    __bf16* xs16  = (__bf16*)(ws + 92274688);
    float*  dbc   = (float*)(ws + 109051904);
    __bf16* ys16  = (__bf16*)(ws + 110362624);
    __bf16* wx16  = (__bf16*)(ws + 127139840);
    __bf16* wdt16 = (__bf16*)(ws + 129236992);

    dim3 blk(256);

    // 0) all casts + zero-inits in ONE dispatch
    fused_cast<<<dim3(15424), blk, 0, stream>>>(
        x, in_proj_w, out_proj_w, x_proj_w, dt_proj_w,
        x16, wi16, wo16, wx16, wdt16, (__bf16*)dbc);

    // 1) xz16 = x @ in_proj_w^T  (M=2048, N=8192, K=2048; KSTEP=64)
    gemm_bf16_nt<0, 64, __bf16><<<dim3(64, 16, 1), blk, 0, stream>>>(
        x16, 2048, wi16, 2048, xz16, 8192, 2048, 8192, nullptr);

    // 2) conv + silu -> xs16, new_conv_cache
    conv_silu<<<dim3(TT / TC, D_INNER / 256, NB), blk, 0, stream>>>(
        xz16, conv_cache, conv_w, conv_b, xs16, cc_out);

    // 3) dbc = xs @ x_proj_w^T  (split-K=8, atomic; N=160 guarded)
    gemm_bf16_nt<2, 32, float><<<dim3(2, 16, 8), blk, 0, stream>>>(
        xs16, 4096, wx16, 4096, dbc, 160, 512, 160, nullptr);

    // 4) delta = softplus(dbc[:, :128] @ dt_proj_w^T + b)  (inlined A cast)
    gemm_dt<<<dim3(32, 16), blk, 0, stream>>>(dbc, wdt16, delta, dt_proj_b);

    // 5) chunked selective scan (2 phases) -> ys16 + h_out
    scan_phase_a<<<dim3(NB * D_INNER * NC * 4 / 256), blk, 0, stream>>>(
        delta, dbc, xs16, A_log, Pbuf, Sbuf);
    scan_phase_c<<<dim3(NB * D_INNER * NC * 4 / 256), blk, 0, stream>>>(
        delta, xz16, dbc, xs16, Pbuf, Sbuf, h_in, A_log, D_param, ys16, h_out);

    // 6) out = ys @ out_proj_w^T  (split-K=4, atomic into zeroed out)
    hipMemsetAsync(out, 0, (size_t)M_TOT * D_MODEL * 4, stream);
    gemm_bf16_nt<2, 64, float><<<dim3(16, 16, 4), blk, 0, stream>>>(
        ys16, 4096, wo16, 4096, out, 2048, 1024, 2048, nullptr);
}

// Round 7
// 489.311 us; speedup vs baseline: 6.3839x; 1.0317x over previous
//
#include <hip/hip_runtime.h>
#include <hip/hip_bf16.h>
#include <math.h>

#define D_MODEL 2048
#define D_INNER 4096
#define D_STATE 16
#define D_CONV  4
#define DT_RANK 128
#define NB      2
#define TT      1024
#define M_TOT   (NB * TT)          // 2048 rows for all GEMMs
#define NC      16                 // scan chunks
#define CL      64                 // chunk length (TT/NC)
#define TC      16                 // conv t-chunk

typedef __bf16 bf16x8_t __attribute__((ext_vector_type(8)));
typedef float  f32x4_t  __attribute__((ext_vector_type(4)));

// ---------------------------------------------------------------------------
// Fused cast/zero kernel: one dispatch does all fp32->bf16 casts plus ALL
// zero-inits (wx16 pad rows, dbc accumulator, out accumulator).  Segments in
// 8-bf16 (16-byte) units:
//   [0,524288)            x      -> x16
//   [524288,2621440)      wi     -> wi16
//   [2621440,3670016)     wo     -> wo16
//   [3670016,3751936)     wx     -> wx16 (data rows)
//   [3751936,3801088)     zeros  -> wx16 (pad rows)
//   [3801088,3866624)     wdt    -> wdt16
//   [3866624,3948544)     zeros  -> dbc  (fp32 accum region)
//   [3948544,4997120)     zeros  -> out  (fp32 accum region, 16.8 MB)
// ---------------------------------------------------------------------------
__global__ __launch_bounds__(256) void fused_cast(
    const float* __restrict__ x,  const float* __restrict__ wi,
    const float* __restrict__ wo, const float* __restrict__ wx,
    const float* __restrict__ wdt,
    __bf16* __restrict__ x16,  __bf16* __restrict__ wi16,
    __bf16* __restrict__ wo16, __bf16* __restrict__ wx16,
    __bf16* __restrict__ wdt16, __bf16* __restrict__ dbc16,
    __bf16* __restrict__ out16)
{
    const size_t g = (size_t)blockIdx.x * 256 + threadIdx.x;
    const float* src; __bf16* dst; size_t off;
    if      (g < 524288)  { src = x;   dst = x16;   off = g; }
    else if (g < 2621440) { src = wi;  dst = wi16;  off = g - 524288; }
    else if (g < 3670016) { src = wo;  dst = wo16;  off = g - 2621440; }
    else if (g < 3801088) { off = g - 3670016; dst = wx16;
                            src = (g < 3751936) ? wx : nullptr; }
    else if (g < 3866624) { src = wdt; dst = wdt16; off = g - 3801088; }
    else if (g < 3948544) { src = nullptr; dst = dbc16; off = g - 3866624; }
    else                  { src = nullptr; dst = out16; off = g - 3948544; }

    bf16x8_t v;
    if (src) {
        const float4 f0 = ((const float4*)src)[2 * off];
        const float4 f1 = ((const float4*)src)[2 * off + 1];
        v[0] = (__bf16)f0.x; v[1] = (__bf16)f0.y; v[2] = (__bf16)f0.z; v[3] = (__bf16)f0.w;
        v[4] = (__bf16)f1.x; v[5] = (__bf16)f1.y; v[6] = (__bf16)f1.z; v[7] = (__bf16)f1.w;
    } else {
        v = (bf16x8_t)(__bf16)0.f;   // bit pattern 0 == fp32 0.0 for zeroed fp32 dst
    }
    ((bf16x8_t*)dst)[off] = v;
}

// ---------------------------------------------------------------------------
// bf16 MFMA GEMM: C(M,Nmax) OutT (+EPI) = A(M,K;lda) bf16 @ W(N,K;ldw)^T.
// 128x128 tile, 256 threads (4 waves).  KSTEP = 32 or 64 (panels per barrier).
// Split-K via gridDim.z.  EPI: 0 store, 1 +bias softplus, 2 atomicAdd.
// ---------------------------------------------------------------------------
template <int EPI, int KSTEP, typename OutT>
__global__ __launch_bounds__(256) void gemm_bf16_nt(
    const __bf16* __restrict__ A, int lda,
    const __bf16* __restrict__ W, int ldw,
    OutT* __restrict__ C, int ldc,
    int Kloop, int Nmax, const float* __restrict__ bias)
{
    __shared__ __bf16 As[128 * KSTEP];
    __shared__ __bf16 Bs[128 * KSTEP];

    const int tid  = threadIdx.x;
    const int wave = tid >> 6;
    const int lane = tid & 63;
    const int m0 = blockIdx.y * 128;
    const int n0 = blockIdx.x * 128;
    const int mw = (wave >> 1) * 64;
    const int nw = (wave & 1) * 64;
    const int koff = blockIdx.z * Kloop;

    f32x4_t acc[4][4] = {};

    const int g0 = wave * 2;
    const int rA = g0 * 16 + (lane >> 2);
    const int kk = (lane & 3) * 8;

    const __bf16* gA0 = A + (size_t)(m0 + rA) * lda + kk + koff;
    const __bf16* gA1 = gA0 + (size_t)16 * lda;
    const __bf16* gB0 = W + (size_t)(n0 + rA) * ldw + kk + koff;
    const __bf16* gB1 = gB0 + (size_t)16 * ldw;

    __bf16* lA0 = &As[(size_t)g0 * 512];
    __bf16* lA1 = &As[(size_t)(g0 + 1) * 512];
    __bf16* lB0 = &Bs[(size_t)g0 * 512];
    __bf16* lB1 = &Bs[(size_t)(g0 + 1) * 512];

    const int fr = lane & 15;
    const int fk = (lane >> 4) * 8;

    for (int k0 = 0; k0 < Kloop; k0 += KSTEP) {
#pragma unroll
        for (int p = 0; p < KSTEP / 32; p++) {
            const int kp = k0 + p * 32;
            const int lp = p * 4096;   // panel offset (elements)
            __builtin_amdgcn_global_load_lds(
                (const __attribute__((address_space(1))) void*)(gA0 + kp),
                (__attribute__((address_space(3))) void*)(lA0 + lp), 16, 0, 0);
            __builtin_amdgcn_global_load_lds(
                (const __attribute__((address_space(1))) void*)(gA1 + kp),
                (__attribute__((address_space(3))) void*)(lA1 + lp), 16, 0, 0);
            __builtin_amdgcn_global_load_lds(
                (const __attribute__((address_space(1))) void*)(gB0 + kp),
                (__attribute__((address_space(3))) void*)(lB0 + lp), 16, 0, 0);
            __builtin_amdgcn_global_load_lds(
                (const __attribute__((address_space(1))) void*)(gB1 + kp),
                (__attribute__((address_space(3))) void*)(lB1 + lp), 16, 0, 0);
        }
        __syncthreads();

#pragma unroll
        for (int p = 0; p < KSTEP / 32; p++) {
            const int lp = p * 4096;
            bf16x8_t av[4], bv[4];
#pragma unroll
            for (int mt = 0; mt < 4; mt++)
                av[mt] = *(const bf16x8_t*)&As[lp + (mw + mt * 16 + fr) * 32 + fk];
#pragma unroll
            for (int nt = 0; nt < 4; nt++)
                bv[nt] = *(const bf16x8_t*)&Bs[lp + (nw + nt * 16 + fr) * 32 + fk];

#pragma unroll
            for (int mt = 0; mt < 4; mt++)
#pragma unroll
                for (int nt = 0; nt < 4; nt++)
                    acc[mt][nt] = __builtin_amdgcn_mfma_f32_16x16x32_bf16(
                        av[mt], bv[nt], acc[mt][nt], 0, 0, 0);
        }
        __syncthreads();
    }

    // C/D layout: col = lane&15, row = (lane>>4)*4 + reg
    const int cn = n0 + nw + (lane & 15);
    const int rb = m0 + mw + (lane >> 4) * 4;
#pragma unroll
    for (int mt = 0; mt < 4; mt++)
#pragma unroll
        for (int nt = 0; nt < 4; nt++) {
            const int n = cn + nt * 16;
            if (n >= Nmax) continue;
#pragma unroll
            for (int r = 0; r < 4; r++) {
                float v = acc[mt][nt][r];
                OutT* p = &C[(size_t)(rb + mt * 16 + r) * ldc + n];
                if (EPI == 1) {
                    v += bias[n];
                    v = (v > 20.f) ? v : log1pf(__expf(v));
                    *p = (OutT)v;
                } else if (EPI == 2) {
                    atomicAdd((float*)p, v);
                } else {
                    *p = (OutT)v;
                }
            }
        }
}

// ---------------------------------------------------------------------------
// dt_proj GEMM with inlined fp32->bf16 A staging.
// delta16(2048,4096) = bf16(softplus(dbc[:,0:128] @ wdt16^T + bias)).
// ---------------------------------------------------------------------------
__global__ __launch_bounds__(256) void gemm_dt(
    const float* __restrict__ A,      // dbc (ld 160)
    const __bf16* __restrict__ W,     // wdt16 (4096,128)
    __bf16* __restrict__ C,           // delta16 (ld 4096)
    const float* __restrict__ bias)
{
    __shared__ __bf16 As[128 * 32];
    __shared__ __bf16 Bs[128 * 32];

    const int tid  = threadIdx.x;
    const int wave = tid >> 6;
    const int lane = tid & 63;
    const int m0 = blockIdx.y * 128;
    const int n0 = blockIdx.x * 128;
    const int mw = (wave >> 1) * 64;
    const int nw = (wave & 1) * 64;

    f32x4_t acc[4][4] = {};

    const int g0 = wave * 2;
    const int rA = g0 * 16 + (lane >> 2);
    const int kk = (lane & 3) * 8;

    const float*  gA0 = A + (size_t)(m0 + rA) * 160 + kk;
    const float*  gA1 = gA0 + (size_t)16 * 160;
    const __bf16* gB0 = W + (size_t)(n0 + rA) * 128 + kk;
    const __bf16* gB1 = gB0 + (size_t)16 * 128;

    __bf16* lA0 = &As[(size_t)g0 * 512];
    __bf16* lA1 = &As[(size_t)(g0 + 1) * 512];
    __bf16* lB0 = &Bs[(size_t)g0 * 512];
    __bf16* lB1 = &Bs[(size_t)(g0 + 1) * 512];

    const int fr = lane & 15;
    const int fk = (lane >> 4) * 8;

    for (int k0 = 0; k0 < 128; k0 += 32) {
        const float4 a0 = *(const float4*)(gA0 + k0);
        const float4 a1 = *(const float4*)(gA0 + k0 + 4);
        const float4 a2 = *(const float4*)(gA1 + k0);
        const float4 a3 = *(const float4*)(gA1 + k0 + 4);
        bf16x8_t va, vb;
        va[0] = (__bf16)a0.x; va[1] = (__bf16)a0.y; va[2] = (__bf16)a0.z; va[3] = (__bf16)a0.w;
        va[4] = (__bf16)a1.x; va[5] = (__bf16)a1.y; va[6] = (__bf16)a1.z; va[7] = (__bf16)a1.w;
        vb[0] = (__bf16)a2.x; vb[1] = (__bf16)a2.y; vb[2] = (__bf16)a2.z; vb[3] = (__bf16)a2.w;
        vb[4] = (__bf16)a3.x; vb[5] = (__bf16)a3.y; vb[6] = (__bf16)a3.z; vb[7] = (__bf16)a3.w;
        ((bf16x8_t*)lA0)[lane] = va;
        ((bf16x8_t*)lA1)[lane] = vb;
        __builtin_amdgcn_global_load_lds(
            (const __attribute__((address_space(1))) void*)(gB0 + k0),
            (__attribute__((address_space(3))) void*)lB0, 16, 0, 0);
        __builtin_amdgcn_global_load_lds(
            (const __attribute__((address_space(1))) void*)(gB1 + k0),
            (__attribute__((address_space(3))) void*)lB1, 16, 0, 0);
        __syncthreads();

        bf16x8_t av[4], bv[4];
#pragma unroll
        for (int mt = 0; mt < 4; mt++)
            av[mt] = *(const bf16x8_t*)&As[(mw + mt * 16 + fr) * 32 + fk];
#pragma unroll
        for (int nt = 0; nt < 4; nt++)
            bv[nt] = *(const bf16x8_t*)&Bs[(nw + nt * 16 + fr) * 32 + fk];

#pragma unroll
        for (int mt = 0; mt < 4; mt++)
#pragma unroll
            for (int nt = 0; nt < 4; nt++)
                acc[mt][nt] = __builtin_amdgcn_mfma_f32_16x16x32_bf16(
                    av[mt], bv[nt], acc[mt][nt], 0, 0, 0);
        __syncthreads();
    }

    const int cn = n0 + nw + (lane & 15);
    const int rb = m0 + mw + (lane >> 4) * 4;
#pragma unroll
    for (int mt = 0; mt < 4; mt++)
#pragma unroll
        for (int nt = 0; nt < 4; nt++) {
            const int n = cn + nt * 16;
            const float bs = bias[n];
#pragma unroll
            for (int r = 0; r < 4; r++) {
                float v = acc[mt][nt][r] + bs;
                v = (v > 20.f) ? v : log1pf(__expf(v));
                C[(size_t)(rb + mt * 16 + r) * 4096 + n] = (__bf16)v;
            }
        }
}

// ---------------------------------------------------------------------------
// Causal depthwise conv (width 4) + bias + silu, t-chunk TC per thread.
// ---------------------------------------------------------------------------
__global__ __launch_bounds__(256) void conv_silu(
    const __bf16* __restrict__ xz16,
    const float* __restrict__ conv_cache,
    const float* __restrict__ conv_w,
    const float* __restrict__ conv_b,
    __bf16* __restrict__ xs16,
    float* __restrict__ cc_out)
{
    const int b  = blockIdx.z;
    const int d  = blockIdx.y * 256 + threadIdx.x;
    const int t0 = blockIdx.x * TC;

    const float4 w  = *(const float4*)&conv_w[d * 4];
    const float bias = conv_b[d];

    float v[TC + 3];
    if (t0 == 0) {
        v[0] = conv_cache[(b * D_INNER + d) * 3 + 0];
        v[1] = conv_cache[(b * D_INNER + d) * 3 + 1];
        v[2] = conv_cache[(b * D_INNER + d) * 3 + 2];
    } else {
        v[0] = (float)xz16[(size_t)(b * TT + t0 - 3) * 8192 + d];
        v[1] = (float)xz16[(size_t)(b * TT + t0 - 2) * 8192 + d];
        v[2] = (float)xz16[(size_t)(b * TT + t0 - 1) * 8192 + d];
    }
#pragma unroll
    for (int k = 0; k < TC; k++)
        v[k + 3] = (float)xz16[(size_t)(b * TT + t0 + k) * 8192 + d];

#pragma unroll
    for (int k = 0; k < TC; k++) {
        float c = v[k] * w.x + v[k + 1] * w.y + v[k + 2] * w.z + v[k + 3] * w.w + bias;
        float s = c / (1.f + __expf(-c));
        xs16[(size_t)(b * TT + t0 + k) * 4096 + d] = (__bf16)s;
    }

    if (t0 + TC == TT) {
        cc_out[(b * D_INNER + d) * 3 + 0] = v[TC];
        cc_out[(b * D_INNER + d) * 3 + 1] = v[TC + 1];
        cc_out[(b * D_INNER + d) * 3 + 2] = v[TC + 2];
    }
}

// ---------------------------------------------------------------------------
// Chunked selective scan (2 phases).  P/S layout: ((b*NC+c)*4096+d)*16+n.
// ---------------------------------------------------------------------------
__global__ __launch_bounds__(256) void scan_phase_a(
    const __bf16* __restrict__ delta16,  // (2048,4096)
    const float* __restrict__ dbc,       // (2048,160): B at 128
    const __bf16* __restrict__ xs16,
    const float* __restrict__ A_log,
    float* __restrict__ P,
    float* __restrict__ S)
{
    const int idx = blockIdx.x * 256 + threadIdx.x;
    const int sub = idx & 3;
    const int d   = (idx >> 2) & 4095;
    const int c   = (idx >> 14) & (NC - 1);
    const int b   = idx >> 18;

    const float4 Af = *(const float4*)&A_log[d * 16 + sub * 4];
    const float Ad0 = -__expf(Af.x), Ad1 = -__expf(Af.y);
    const float Ad2 = -__expf(Af.z), Ad3 = -__expf(Af.w);

    const int t0 = c * CL;
    const __bf16* pdelta = delta16 + (size_t)(b * TT + t0) * 4096 + d;
    const __bf16* px     = xs16 + (size_t)(b * TT + t0) * 4096 + d;
    const float*  pB     = dbc + ((size_t)b * TT + t0) * 160 + 128 + sub * 4;

    float h0 = 0.f, h1 = 0.f, h2 = 0.f, h3 = 0.f, sd = 0.f;
#pragma unroll 4
    for (int t = 0; t < CL; t++) {
        const float delta = (float)pdelta[(size_t)t * 4096];
        const float xv    = (float)px[(size_t)t * 4096];
        const float4 Bv   = *(const float4*)&pB[(size_t)t * 160];
        const float dx = delta * xv;
        h0 = __expf(delta * Ad0) * h0 + dx * Bv.x;
        h1 = __expf(delta * Ad1) * h1 + dx * Bv.y;
        h2 = __expf(delta * Ad2) * h2 + dx * Bv.z;
        h3 = __expf(delta * Ad3) * h3 + dx * Bv.w;
        sd += delta;
    }
    const size_t o = ((size_t)(b * NC + c) * 4096 + d) * 16 + sub * 4;
    *(float4*)&P[o] = make_float4(__expf(Ad0 * sd), __expf(Ad1 * sd),
                                  __expf(Ad2 * sd), __expf(Ad3 * sd));
    *(float4*)&S[o] = make_float4(h0, h1, h2, h3);
}

__global__ __launch_bounds__(256) void scan_phase_c(
    const __bf16* __restrict__ delta16,
    const __bf16* __restrict__ xz16,     // z at cols 4096:8192
    const float* __restrict__ dbc,       // B at 128, C at 144
    const __bf16* __restrict__ xs16,
    const float* __restrict__ P,         // chunk decay
    const float* __restrict__ S,         // chunk local scan
    const float* __restrict__ h_in,
    const float* __restrict__ A_log,
    const float* __restrict__ D_param,
    __bf16* __restrict__ ys16,
    float* __restrict__ h_out)
{
    const int idx = blockIdx.x * 256 + threadIdx.x;
    const int sub = idx & 3;
    const int d   = (idx >> 2) & 4095;
    const int c   = (idx >> 14) & (NC - 1);   // block-uniform
    const int b   = idx >> 18;

    const float4 Af = *(const float4*)&A_log[d * 16 + sub * 4];
    const float Ad0 = -__expf(Af.x), Ad1 = -__expf(Af.y);
    const float Ad2 = -__expf(Af.z), Ad3 = -__expf(Af.w);
    const float Dp = D_param[d];

    // h_start = combine(h_in, chunks 0..c-1)
    float4 hf = *(const float4*)&h_in[((size_t)b * 4096 + d) * 16 + sub * 4];
    float h0 = hf.x, h1 = hf.y, h2 = hf.z, h3 = hf.w;
    for (int cc = 0; cc < c; cc++) {
        const size_t o2 = ((size_t)(b * NC + cc) * 4096 + d) * 16 + sub * 4;
        const float4 p = *(const float4*)&P[o2];
        const float4 s = *(const float4*)&S[o2];
        h0 = p.x * h0 + s.x;
        h1 = p.y * h1 + s.y;
        h2 = p.z * h2 + s.z;
        h3 = p.w * h3 + s.w;
    }

    const int t0 = c * CL;
    const __bf16* pdelta = delta16 + (size_t)(b * TT + t0) * 4096 + d;
    const __bf16* pz     = xz16 + (size_t)(b * TT + t0) * 8192 + 4096 + d;
    const __bf16* px     = xs16 + (size_t)(b * TT + t0) * 4096 + d;
    const float*  pB     = dbc + ((size_t)b * TT + t0) * 160 + 128 + sub * 4;
    const float*  pC     = pB + 16;
    __bf16* py = ys16 + (size_t)(b * TT + t0) * 4096 + d;

#pragma unroll 4
    for (int t = 0; t < CL; t++) {
        const float delta = (float)pdelta[(size_t)t * 4096];
        const float xv    = (float)px[(size_t)t * 4096];
        const float4 Bv   = *(const float4*)&pB[(size_t)t * 160];
        const float4 Cv   = *(const float4*)&pC[(size_t)t * 160];
        const float dx = delta * xv;

        h0 = __expf(delta * Ad0) * h0 + dx * Bv.x;
        h1 = __expf(delta * Ad1) * h1 + dx * Bv.y;
        h2 = __expf(delta * Ad2) * h2 + dx * Bv.z;
        h3 = __expf(delta * Ad3) * h3 + dx * Bv.w;

        float y = h0 * Cv.x + h1 * Cv.y + h2 * Cv.z + h3 * Cv.w;
        y += __shfl_xor(y, 1);
        y += __shfl_xor(y, 2);

        if (sub == 0) {
            const float zv = (float)pz[(size_t)t * 8192];
            y += Dp * xv;
            const float g = zv / (1.f + __expf(-zv));
            py[(size_t)t * 4096] = (__bf16)(y * g);
        }
    }

    if (c == NC - 1) {
        *(float4*)&h_out[((size_t)b * 4096 + d) * 16 + sub * 4] =
            make_float4(h0, h1, h2, h3);
    }
}

// ---------------------------------------------------------------------------
extern "C" void kernel_launch(void* const* d_in, const int* in_sizes, int n_in,
                              void* d_out, int out_size, void* d_ws, size_t ws_size,
                              hipStream_t stream)
{
    const float* x          = (const float*)d_in[0];
    const float* h_in       = (const float*)d_in[1];
    const float* conv_cache = (const float*)d_in[2];
    const float* in_proj_w  = (const float*)d_in[3];
    const float* conv_w     = (const float*)d_in[4];
    const float* conv_b     = (const float*)d_in[5];
    const float* x_proj_w   = (const float*)d_in[6];
    const float* dt_proj_w  = (const float*)d_in[7];
    const float* dt_proj_b  = (const float*)d_in[8];
    const float* A_log      = (const float*)d_in[9];
    const float* D_param    = (const float*)d_in[10];
    const float* out_proj_w = (const float*)d_in[11];

    float* out    = (float*)d_out;
    float* h_out  = (float*)d_out + (size_t)NB * TT * D_MODEL;
    float* cc_out = h_out + (size_t)NB * D_INNER * D_STATE;

    char* ws = (char*)d_ws;
    // [0, 33.5M)       xz16 bf16 (2048x8192): xi | z
    // [33.5M, 41.9M)   x16 bf16 (2048x2048)   -- dead after in_proj -> Pbuf
    // [41.9M, 75.5M)   wi16 bf16 (8192x2048)  -- dead after in_proj:
    //                    [41.9M,58.7M) delta16 bf16 (2048x4096)
    //                    [58.7M,67.1M) Sbuf fp32
    // [75.5M, 92.3M)   wo16 bf16 (2048x4096)
    // [92.3M, 109M)    xs16 bf16 (2048x4096)
    // [109M, 110.4M)   dbc fp32 (2048x160)
    // [110.4M, 127.1M) ys16 bf16 (2048x4096)
    // [127.1M, 129.2M) wx16 bf16 (256x4096, padded)
    // [129.2M, 130.3M) wdt16 bf16 (4096x128)
    __bf16* xz16    = (__bf16*)(ws);
    __bf16* x16     = (__bf16*)(ws + 33554432);
    float*  Pbuf    = (float*)(ws + 33554432);    // aliases x16 (after in_proj)
    __bf16* wi16    = (__bf16*)(ws + 41943040);
    __bf16* delta16 = (__bf16*)(ws + 41943040);   // aliases wi16 (after in_proj)
    float*  Sbuf    = (float*)(ws + 58720256);    // aliases wi16 tail
    __bf16* wo16    = (__bf16*)(ws + 75497472);
    __bf16* xs16    = (__bf16*)(ws + 92274688);
    float*  dbc     = (float*)(ws + 109051904);
    __bf16* ys16    = (__bf16*)(ws + 110362624);
    __bf16* wx16    = (__bf16*)(ws + 127139840);
    __bf16* wdt16   = (__bf16*)(ws + 129236992);

    dim3 blk(256);

    // 0) all casts + all zero-inits (wx pad, dbc, out) in ONE dispatch
    fused_cast<<<dim3(19520), blk, 0, stream>>>(
        x, in_proj_w, out_proj_w, x_proj_w, dt_proj_w,
        x16, wi16, wo16, wx16, wdt16, (__bf16*)dbc, (__bf16*)out);

    // 1) xz16 = x @ in_proj_w^T  (M=2048, N=8192, K=2048; KSTEP=64)
    gemm_bf16_nt<0, 64, __bf16><<<dim3(64, 16, 1), blk, 0, stream>>>(
        x16, 2048, wi16, 2048, xz16, 8192, 2048, 8192, nullptr);

    // 2) conv + silu -> xs16, new_conv_cache
    conv_silu<<<dim3(TT / TC, D_INNER / 256, NB), blk, 0, stream>>>(
        xz16, conv_cache, conv_w, conv_b, xs16, cc_out);

    // 3) dbc = xs @ x_proj_w^T  (split-K=16, atomic; N=160 guarded)
    gemm_bf16_nt<2, 32, float><<<dim3(2, 16, 16), blk, 0, stream>>>(
        xs16, 4096, wx16, 4096, dbc, 160, 256, 160, nullptr);

    // 4) delta16 = bf16(softplus(dbc[:, :128] @ dt_proj_w^T + b))
    gemm_dt<<<dim3(32, 16), blk, 0, stream>>>(dbc, wdt16, delta16, dt_proj_b);

    // 5) chunked selective scan (2 phases) -> ys16 + h_out
    scan_phase_a<<<dim3(NB * D_INNER * NC * 4 / 256), blk, 0, stream>>>(
        delta16, dbc, xs16, A_log, Pbuf, Sbuf);
    scan_phase_c<<<dim3(NB * D_INNER * NC * 4 / 256), blk, 0, stream>>>(
        delta16, xz16, dbc, xs16, Pbuf, Sbuf, h_in, A_log, D_param, ys16, h_out);

    // 6) out = ys @ out_proj_w^T  (split-K=2, atomic into pre-zeroed out)
    gemm_bf16_nt<2, 64, float><<<dim3(16, 16, 2), blk, 0, stream>>>(
        ys16, 4096, wo16, 4096, out, 2048, 2048, 2048, nullptr);
}